// Round 4
// baseline (580.044 us; speedup 1.0000x reference)
//
#include <hip/hip_runtime.h>
#include <math.h>

typedef long long ll;
typedef unsigned int u32;
typedef unsigned short u16;

__device__ __forceinline__ int load_idx(const void* p, int i, int is64) {
  return is64 ? (int)((const ll*)p)[i] : ((const int*)p)[i];
}

__device__ __forceinline__ u16 f2bf(float f) {
  u32 u = __float_as_uint(f);
  u += 0x7FFFu + ((u >> 16) & 1u);
  return (u16)(u >> 16);
}

// ---------- detect whether integer inputs are int64 or int32 ----------
__global__ void detect_kernel(const void* __restrict__ eidx, int ne,
                              const void* __restrict__ batch, int nb,
                              int* __restrict__ flags) {
  if (threadIdx.x == 0 && blockIdx.x == 0) {
    int e64 = 1;
    for (int k = 1; k <= 16; ++k) {
      int i = (int)((ll)k * (ne / 2 - 1) / 16);
      ll v = ((const ll*)eidx)[i];
      if (v < 0 || v >= (1LL << 31)) { e64 = 0; break; }
    }
    int b64 = 1;
    for (int k = 1; k <= 16; ++k) {
      int i = (int)((ll)k * (nb / 2 - 1) / 16);
      ll v = ((const ll*)batch)[i];
      if (v < 0 || v >= (1LL << 31)) { b64 = 0; break; }
    }
    flags[0] = e64; flags[1] = b64;
  }
}

// ---------- zero init (re-run every call) ----------
__global__ void zero_kernel(int* __restrict__ bcnt, float* __restrict__ pool, int nc) {
  int i = blockIdx.x * blockDim.x + threadIdx.x;
  if (i < nc) bcnt[i] = 0;
  if (i < 192) pool[i] = 0.f;
}

// ---------- K1: h = x @ W1 (f32 acc, bf16 store; fused a_src1/a_dst1) ----------
__global__ __launch_bounds__(256) void gemm1_kernel(
    const float* __restrict__ x, const float* __restrict__ W1,
    const float* __restrict__ att_src, const float* __restrict__ att_dst,
    u16* __restrict__ h, float* __restrict__ a_src, float* __restrict__ a_dst,
    int nn) {
  __shared__ float4 Ws[128][32];   // 64 KB
  __shared__ float xs[32][128];    // 16 KB
  int t = threadIdx.x;
  const float4* W4 = (const float4*)W1;
  #pragma unroll
  for (int i = 0; i < 16; ++i) {
    int f = t + i * 256;           // 4096 float4s
    Ws[f >> 5][f & 31] = W4[f];
  }
  int q = t & 31, p = t >> 5;
  int n0 = blockIdx.x * 64;
  const float4 as4 = ((const float4*)att_src)[q];
  const float4 ad4 = ((const float4*)att_dst)[q];
  for (int g = 0; g < 64; g += 32) {
    __syncthreads();
    #pragma unroll
    for (int i = 0; i < 4; ++i) {
      int f = t + i * 256;         // 1024 float4s = 32 rows
      int node = f >> 5, c4 = f & 31;
      int gn = n0 + g + node;
      float4 v = make_float4(0.f, 0.f, 0.f, 0.f);
      if (gn < nn) v = ((const float4*)x)[(size_t)gn * 32 + c4];
      *(float4*)&xs[node][c4 << 2] = v;
    }
    __syncthreads();
    float4 acc[4];
    #pragma unroll
    for (int r = 0; r < 4; ++r) acc[r] = make_float4(0.f, 0.f, 0.f, 0.f);
    #pragma unroll 4
    for (int k = 0; k < 128; ++k) {
      float4 w = Ws[k][q];
      #pragma unroll
      for (int r = 0; r < 4; ++r) {
        float xv = xs[p + r * 8][k];
        acc[r].x = fmaf(xv, w.x, acc[r].x);
        acc[r].y = fmaf(xv, w.y, acc[r].y);
        acc[r].z = fmaf(xv, w.z, acc[r].z);
        acc[r].w = fmaf(xv, w.w, acc[r].w);
      }
    }
    int head = q >> 2;
    #pragma unroll
    for (int r = 0; r < 4; ++r) {
      int n = n0 + g + p + r * 8;
      float s = acc[r].x*as4.x + acc[r].y*as4.y + acc[r].z*as4.z + acc[r].w*as4.w;
      float d = acc[r].x*ad4.x + acc[r].y*ad4.y + acc[r].z*ad4.z + acc[r].w*ad4.w;
      s += __shfl_xor(s, 1); s += __shfl_xor(s, 2);
      d += __shfl_xor(d, 1); d += __shfl_xor(d, 2);
      if (n < nn) {
        uint2 pk;
        pk.x = (u32)f2bf(acc[r].x) | ((u32)f2bf(acc[r].y) << 16);
        pk.y = (u32)f2bf(acc[r].z) | ((u32)f2bf(acc[r].w) << 16);
        ((uint2*)(h + (size_t)n * 128))[q] = pk;
        if ((q & 3) == 0) { a_src[n * 8 + head] = s; a_dst[n * 8 + head] = d; }
      }
    }
  }
}

// ---------- bucket histogram: counter per (dst>>8, blockIdx&7) ----------
__global__ void bhist_kernel(const void* __restrict__ eidx, int E, int EP,
                             const int* __restrict__ flags, int* __restrict__ bcnt) {
  int i = blockIdx.x * blockDim.x + threadIdx.x;
  if (i >= EP) return;
  int is64 = flags[0];
  int d = (i < E) ? load_idx(eidx, E + i, is64) : (i - E);
  int c = ((d >> 8) << 3) + (blockIdx.x & 7);
  atomicAdd(&bcnt[c], 1);
}

// ---------- single-block scan of the small counter array ----------
__global__ __launch_bounds__(1024) void bscan_kernel(
    const int* __restrict__ bcnt, int* __restrict__ cur,
    int* __restrict__ base, int nc) {
  int t = threadIdx.x;
  int v[4]; int s = 0;
  #pragma unroll
  for (int u = 0; u < 4; ++u) {
    int i = t * 4 + u;
    v[u] = (i < nc) ? bcnt[i] : 0;
    s += v[u];
  }
  int lane = t & 63, w = t >> 6;
  int ps = s;
  #pragma unroll
  for (int off = 1; off < 64; off <<= 1) {
    int u = __shfl_up(ps, off);
    if (lane >= off) ps += u;
  }
  __shared__ int ws[16];
  if (lane == 63) ws[w] = ps;
  __syncthreads();
  int add = 0;
  for (int k = 0; k < w; ++k) add += ws[k];
  int run = ps + add - s;   // exclusive prefix at this thread's first item
  #pragma unroll
  for (int u = 0; u < 4; ++u) {
    int i = t * 4 + u;
    if (i < nc) { cur[i] = run; base[i] = run; }
    run += v[u];
  }
}

// ---------- scatter (s,d) pairs into XCD-class-local dense sub-segments ----------
__global__ void bscatter_kernel(const void* __restrict__ eidx, int E, int EP,
                                const int* __restrict__ flags,
                                int* __restrict__ cur, uint2* __restrict__ pairs) {
  int i = blockIdx.x * blockDim.x + threadIdx.x;
  if (i >= EP) return;
  int is64 = flags[0];
  int s, d;
  if (i < E) { s = load_idx(eidx, i, is64); d = load_idx(eidx, E + i, is64); }
  else { s = d = i - E; }
  int c = ((d >> 8) << 3) + (blockIdx.x & 7);
  int pos = atomicAdd(&cur[c], 1);
  pairs[pos] = make_uint2((u32)s, (u32)d);
}

// ---------- per-bucket local sort: LDS hist+scan, write offs/ends/ssrc ----------
__global__ __launch_bounds__(256) void bfinal_kernel(
    const uint2* __restrict__ pairs, const int* __restrict__ base,
    int* __restrict__ offs, int* __restrict__ ends, int* __restrict__ ssrc,
    int N, int EP, int NBUK) {
  int b = blockIdx.x, t = threadIdx.x;
  int nb0 = b << 8;
  __shared__ int cnt[256];
  __shared__ int cur[256];
  __shared__ int wsum[4];
  cnt[t] = 0;
  __syncthreads();
  int seg_start = base[b * 8];
  int seg_end = (b + 1 < NBUK) ? base[(b + 1) * 8] : EP;
  for (int i = seg_start + t; i < seg_end; i += 256) {
    uint2 p = pairs[i];
    atomicAdd(&cnt[p.y - nb0], 1);
  }
  __syncthreads();
  int v = cnt[t];
  int lane = t & 63, w = t >> 6;
  int s = v;
  #pragma unroll
  for (int off = 1; off < 64; off <<= 1) {
    int u = __shfl_up(s, off);
    if (lane >= off) s += u;
  }
  if (lane == 63) wsum[w] = s;
  __syncthreads();
  int add = 0;
  for (int k = 0; k < w; ++k) add += wsum[k];
  int excl = s + add - v;
  cur[t] = excl;
  int node = nb0 + t;
  if (node < N) { offs[node] = seg_start + excl; ends[node] = seg_start + excl + v; }
  __syncthreads();
  for (int i = seg_start + t; i < seg_end; i += 256) {
    uint2 p = pairs[i];
    int pos = atomicAdd(&cur[p.y - nb0], 1);
    ssrc[seg_start + pos] = (int)p.x;
  }
}

// ---------- layer-1 aggregation + ELU + layer-2 projection ----------
__global__ __launch_bounds__(256) void node1_kernel(
    const int* __restrict__ ssrc, const int* __restrict__ offs, const int* __restrict__ ends,
    const u16* __restrict__ h, const float* __restrict__ a_src, const float* __restrict__ a_dst,
    const float* __restrict__ b1, const float* __restrict__ W2,
    const float* __restrict__ att_s2, const float* __restrict__ att_d2,
    float* __restrict__ h2, float* __restrict__ as2, float* __restrict__ ad2, int nn) {
  int wid = threadIdx.x >> 6, lane = threadIdx.x & 63;
  int n = blockIdx.x * 4 + wid;
  if (n >= nn) return;
  int j = lane << 1;
  int hh = lane >> 3;
  float adst = a_dst[n * 8 + hh];
  int beg = offs[n], end = ends[n];   // deg >= 1 (self-loop)
  float acc0 = 0.f, acc1 = 0.f, dsum = 0.f;
  for (int base = beg; base < end; base += 8) {
    int s[8]; u32 v[8]; float ea[8];
    #pragma unroll
    for (int u = 0; u < 8; ++u) {
      int id = base + u;
      s[u] = ssrc[id < end ? id : end - 1];
    }
    #pragma unroll
    for (int u = 0; u < 8; ++u) {
      v[u]  = ((const u32*)(h + (size_t)s[u] * 128))[lane];
      ea[u] = a_src[s[u] * 8 + hh];
    }
    #pragma unroll
    for (int u = 0; u < 8; ++u) {
      float e = ea[u] + adst;
      e = (e < 0.f) ? 0.2f * e : e;
      float ee = (base + u < end) ? __expf(e) : 0.f;
      float h0 = __uint_as_float(v[u] << 16);
      float h1 = __uint_as_float(v[u] & 0xFFFF0000u);
      acc0 = fmaf(ee, h0, acc0);
      acc1 = fmaf(ee, h1, acc1);
      dsum += ee;
    }
  }
  float inv = 1.f / dsum;
  float o0 = acc0 * inv + b1[j];
  float o1 = acc1 * inv + b1[j + 1];
  o0 = (o0 > 0.f) ? o0 : expm1f(o0);   // ELU
  o1 = (o1 > 0.f) ? o1 : expm1f(o1);
  float p0 = o0 * W2[j * 2]     + o1 * W2[(j + 1) * 2];
  float p1 = o0 * W2[j * 2 + 1] + o1 * W2[(j + 1) * 2 + 1];
  #pragma unroll
  for (int m = 1; m < 64; m <<= 1) { p0 += __shfl_xor(p0, m); p1 += __shfl_xor(p1, m); }
  if (lane == 0) {
    h2[n * 2] = p0; h2[n * 2 + 1] = p1;
    as2[n] = p0 * att_s2[0] + p1 * att_s2[1];
    ad2[n] = p0 * att_d2[0] + p1 * att_d2[1];
  }
}

// ---------- layer-2 aggregation + graph mean-pool (8-lane group per node) ----------
__global__ __launch_bounds__(256) void node2_kernel(
    const int* __restrict__ ssrc, const int* __restrict__ offs, const int* __restrict__ ends,
    const float* __restrict__ h2, const float* __restrict__ as2, const float* __restrict__ ad2,
    const float* __restrict__ b2, const void* __restrict__ batch, const int* __restrict__ flags,
    float* __restrict__ pool, int nn) {
  __shared__ float psum[128];
  __shared__ float pcnt[64];
  int t = threadIdx.x;
  if (t < 128) psum[t] = 0.f;
  if (t < 64) pcnt[t] = 0.f;
  __syncthreads();
  int grp = t >> 3, lane8 = t & 7;    // 32 groups of 8 lanes
  int b64 = flags[1];
  int n = blockIdx.x * 32 + grp;
  if (n < nn) {
    float adst = ad2[n];
    int beg = offs[n], end = ends[n];
    float acc0 = 0.f, acc1 = 0.f, dsum = 0.f;
    for (int idx = beg + lane8; idx < end; idx += 8) {
      int s = ssrc[idx];
      float e = as2[s] + adst;
      e = (e < 0.f) ? 0.2f * e : e;
      float ee = __expf(e);
      float2 hv = *(const float2*)(h2 + (size_t)s * 2);
      acc0 = fmaf(ee, hv.x, acc0);
      acc1 = fmaf(ee, hv.y, acc1);
      dsum += ee;
    }
    #pragma unroll
    for (int m = 1; m < 8; m <<= 1) {   // xor mask <8 stays within the 8-group
      acc0 += __shfl_xor(acc0, m);
      acc1 += __shfl_xor(acc1, m);
      dsum += __shfl_xor(dsum, m);
    }
    if (lane8 == 0) {
      float o0 = acc0 / dsum + b2[0];
      float o1 = acc1 / dsum + b2[1];
      int g = load_idx(batch, n, b64);
      atomicAdd(&psum[g * 2], o0);
      atomicAdd(&psum[g * 2 + 1], o1);
      atomicAdd(&pcnt[g], 1.f);
    }
  }
  __syncthreads();
  if (t < 64 && pcnt[t] > 0.f) {
    atomicAdd(&pool[t * 2], psum[t * 2]);
    atomicAdd(&pool[t * 2 + 1], psum[t * 2 + 1]);
    atomicAdd(&pool[128 + t], pcnt[t]);
  }
}

// ---------- mean + log_softmax ----------
__global__ void finalize_kernel(const float* __restrict__ pool, float* __restrict__ out) {
  int g = threadIdx.x;
  if (g < 64) {
    float c = fmaxf(pool[128 + g], 1.f);
    float p0 = pool[g * 2] / c, p1 = pool[g * 2 + 1] / c;
    float m = fmaxf(p0, p1);
    float lse = m + logf(expf(p0 - m) + expf(p1 - m));
    out[g * 2] = p0 - lse;
    out[g * 2 + 1] = p1 - lse;
  }
}

extern "C" void kernel_launch(void* const* d_in, const int* in_sizes, int n_in,
                              void* d_out, int out_size, void* d_ws, size_t ws_size,
                              hipStream_t stream) {
  const float* x        = (const float*)d_in[0];
  const void* eidx      = d_in[1];
  const void* batch     = d_in[2];
  const float* W1       = (const float*)d_in[3];
  const float* att_src1 = (const float*)d_in[4];
  const float* att_dst1 = (const float*)d_in[5];
  const float* b1       = (const float*)d_in[6];
  const float* W2       = (const float*)d_in[7];
  const float* att_src2 = (const float*)d_in[8];
  const float* att_dst2 = (const float*)d_in[9];
  const float* b2       = (const float*)d_in[10];
  float* out = (float*)d_out;

  int N = in_sizes[0] / 128;
  int E = in_sizes[1] / 2;
  int EP = E + N;
  int NBUK = (N + 255) >> 8;
  int NC = NBUK * 8;

  char* ws = (char*)d_ws;
  size_t o = 0;
  auto alloc = [&](size_t bytes) -> void* {
    void* p = ws + o;
    o += (bytes + 255) & ~(size_t)255;
    return p;
  };
  u16*   h      = (u16*)alloc((size_t)N * 128 * 2);    // 25.6 MB bf16
  float* a_src1 = (float*)alloc((size_t)N * 8 * 4);
  float* a_dst1 = (float*)alloc((size_t)N * 8 * 4);
  int*   offs   = (int*)alloc((size_t)N * 4);
  int*   ends   = (int*)alloc((size_t)N * 4);
  int*   bcnt   = (int*)alloc((size_t)NC * 4);
  int*   bcur   = (int*)alloc((size_t)NC * 4);
  int*   bbase  = (int*)alloc((size_t)NC * 4);
  uint2* pairs  = (uint2*)alloc((size_t)EP * 8);       // 13.6 MB
  int*   ssrc   = (int*)alloc((size_t)EP * 4);
  float* h2     = (float*)alloc((size_t)N * 2 * 4);
  float* as2    = (float*)alloc((size_t)N * 4);
  float* ad2    = (float*)alloc((size_t)N * 4);
  float* pool   = (float*)alloc(192 * 4);              // [128] sums + [64] counts
  int*   flags  = (int*)alloc(2 * 4);

  detect_kernel<<<1, 64, 0, stream>>>(eidx, 2 * E, batch, N, flags);
  zero_kernel<<<(NC + 255) / 256, 256, 0, stream>>>(bcnt, pool, NC);
  gemm1_kernel<<<(N + 63) / 64, 256, 0, stream>>>(x, W1, att_src1, att_dst1,
                                                  h, a_src1, a_dst1, N);
  bhist_kernel<<<(EP + 255) / 256, 256, 0, stream>>>(eidx, E, EP, flags, bcnt);
  bscan_kernel<<<1, 1024, 0, stream>>>(bcnt, bcur, bbase, NC);
  bscatter_kernel<<<(EP + 255) / 256, 256, 0, stream>>>(eidx, E, EP, flags, bcur, pairs);
  bfinal_kernel<<<NBUK, 256, 0, stream>>>(pairs, bbase, offs, ends, ssrc, N, EP, NBUK);
  node1_kernel<<<(N + 3) / 4, 256, 0, stream>>>(ssrc, offs, ends, h, a_src1, a_dst1,
                                                b1, W2, att_src2, att_dst2,
                                                h2, as2, ad2, N);
  node2_kernel<<<(N + 31) / 32, 256, 0, stream>>>(ssrc, offs, ends, h2, as2, ad2,
                                                  b2, batch, flags, pool, N);
  finalize_kernel<<<1, 64, 0, stream>>>(pool, out);
}

// Round 5
// 256.904 us; speedup vs baseline: 2.2578x; 2.2578x over previous
//
#include <hip/hip_runtime.h>
#include <math.h>

typedef long long ll;
typedef unsigned int u32;
typedef unsigned short u16;

#define NBLK 256          // partition blocks
#define MAXBUK 512        // supports N <= 131072

__device__ __forceinline__ int load_idx(const void* p, int i, int is64) {
  return is64 ? (int)((const ll*)p)[i] : ((const int*)p)[i];
}

__device__ __forceinline__ u16 f2bf(float f) {
  u32 u = __float_as_uint(f);
  u += 0x7FFFu + ((u >> 16) & 1u);
  return (u16)(u >> 16);
}

// ---------- detect whether integer inputs are int64 or int32 ----------
__global__ void detect_kernel(const void* __restrict__ eidx, int ne,
                              const void* __restrict__ batch, int nb,
                              int* __restrict__ flags) {
  if (threadIdx.x == 0 && blockIdx.x == 0) {
    int e64 = 1;
    for (int k = 1; k <= 16; ++k) {
      int i = (int)((ll)k * (ne / 2 - 1) / 16);
      ll v = ((const ll*)eidx)[i];
      if (v < 0 || v >= (1LL << 31)) { e64 = 0; break; }
    }
    int b64 = 1;
    for (int k = 1; k <= 16; ++k) {
      int i = (int)((ll)k * (nb / 2 - 1) / 16);
      ll v = ((const ll*)batch)[i];
      if (v < 0 || v >= (1LL << 31)) { b64 = 0; break; }
    }
    flags[0] = e64; flags[1] = b64;
  }
}

// ---------- zero pool only (hist zeroed in-kernel) ----------
__global__ void zero_kernel(float* __restrict__ pool) {
  int i = threadIdx.x;
  if (i < 192) pool[i] = 0.f;
}

// ---------- K1: h = x @ W1 (f32 acc, bf16 store; fused a_src1/a_dst1) ----------
__global__ __launch_bounds__(256) void gemm1_kernel(
    const float* __restrict__ x, const float* __restrict__ W1,
    const float* __restrict__ att_src, const float* __restrict__ att_dst,
    u16* __restrict__ h, float* __restrict__ a_src, float* __restrict__ a_dst,
    int nn) {
  __shared__ float4 Ws[128][32];   // 64 KB
  __shared__ float xs[32][128];    // 16 KB
  int t = threadIdx.x;
  const float4* W4 = (const float4*)W1;
  #pragma unroll
  for (int i = 0; i < 16; ++i) {
    int f = t + i * 256;           // 4096 float4s
    Ws[f >> 5][f & 31] = W4[f];
  }
  int q = t & 31, p = t >> 5;
  int n0 = blockIdx.x * 64;
  const float4 as4 = ((const float4*)att_src)[q];
  const float4 ad4 = ((const float4*)att_dst)[q];
  for (int g = 0; g < 64; g += 32) {
    __syncthreads();
    #pragma unroll
    for (int i = 0; i < 4; ++i) {
      int f = t + i * 256;         // 1024 float4s = 32 rows
      int node = f >> 5, c4 = f & 31;
      int gn = n0 + g + node;
      float4 v = make_float4(0.f, 0.f, 0.f, 0.f);
      if (gn < nn) v = ((const float4*)x)[(size_t)gn * 32 + c4];
      *(float4*)&xs[node][c4 << 2] = v;
    }
    __syncthreads();
    float4 acc[4];
    #pragma unroll
    for (int r = 0; r < 4; ++r) acc[r] = make_float4(0.f, 0.f, 0.f, 0.f);
    #pragma unroll 4
    for (int k = 0; k < 128; ++k) {
      float4 w = Ws[k][q];
      #pragma unroll
      for (int r = 0; r < 4; ++r) {
        float xv = xs[p + r * 8][k];
        acc[r].x = fmaf(xv, w.x, acc[r].x);
        acc[r].y = fmaf(xv, w.y, acc[r].y);
        acc[r].z = fmaf(xv, w.z, acc[r].z);
        acc[r].w = fmaf(xv, w.w, acc[r].w);
      }
    }
    int head = q >> 2;
    #pragma unroll
    for (int r = 0; r < 4; ++r) {
      int n = n0 + g + p + r * 8;
      float s = acc[r].x*as4.x + acc[r].y*as4.y + acc[r].z*as4.z + acc[r].w*as4.w;
      float d = acc[r].x*ad4.x + acc[r].y*ad4.y + acc[r].z*ad4.z + acc[r].w*ad4.w;
      s += __shfl_xor(s, 1); s += __shfl_xor(s, 2);
      d += __shfl_xor(d, 1); d += __shfl_xor(d, 2);
      if (n < nn) {
        uint2 pk;
        pk.x = (u32)f2bf(acc[r].x) | ((u32)f2bf(acc[r].y) << 16);
        pk.y = (u32)f2bf(acc[r].z) | ((u32)f2bf(acc[r].w) << 16);
        ((uint2*)(h + (size_t)n * 128))[q] = pk;
        if ((q & 3) == 0) { a_src[n * 8 + head] = s; a_dst[n * 8 + head] = d; }
      }
    }
  }
}

// ---------- per-block LDS histogram of dst buckets (no global atomics) ----------
__global__ __launch_bounds__(512) void ehist_kernel(
    const void* __restrict__ eidx, int E, int EP, int chunk,
    const int* __restrict__ flags, int* __restrict__ hist_g, int nbuk) {
  __shared__ int cnt[MAXBUK];
  int t = threadIdx.x, blk = blockIdx.x;
  if (t < MAXBUK) cnt[t] = 0;
  __syncthreads();
  int lo = blk * chunk, hi = min(lo + chunk, EP);
  int is64 = flags[0];
  for (int i = lo + t; i < hi; i += 512) {
    int d = (i < E) ? load_idx(eidx, E + i, is64) : (i - E);
    atomicAdd(&cnt[d >> 8], 1);
  }
  __syncthreads();
  if (t < nbuk) hist_g[t * NBLK + blk] = cnt[t];
}

// ---------- two-level exclusive scan over nbuk*NBLK counters ----------
__global__ __launch_bounds__(256) void scan_blk(const int* __restrict__ in,
                                                int* __restrict__ out,
                                                int* __restrict__ bsums, int n) {
  int t = threadIdx.x;
  int i = blockIdx.x * 256 + t;
  int v = (i < n) ? in[i] : 0;
  int lane = t & 63, w = t >> 6;
  int s = v;
  #pragma unroll
  for (int off = 1; off < 64; off <<= 1) {
    int u = __shfl_up(s, off);
    if (lane >= off) s += u;
  }
  __shared__ int wsum[4];
  if (lane == 63) wsum[w] = s;
  __syncthreads();
  int add = 0;
  for (int k = 0; k < w; ++k) add += wsum[k];
  int incl = s + add;
  if (i < n) out[i] = incl - v;
  if (t == 255) bsums[blockIdx.x] = incl;
}

__global__ __launch_bounds__(1024) void scan_top(int* __restrict__ bsums, int nb) {
  int t = threadIdx.x;
  int v = (t < nb) ? bsums[t] : 0;
  int lane = t & 63, w = t >> 6;
  int s = v;
  #pragma unroll
  for (int off = 1; off < 64; off <<= 1) {
    int u = __shfl_up(s, off);
    if (lane >= off) s += u;
  }
  __shared__ int ws[16];
  if (lane == 63) ws[w] = s;
  __syncthreads();
  int add = 0;
  for (int k = 0; k < w; ++k) add += ws[k];
  if (t < nb) bsums[t] = s + add - v;
}

__global__ void scan_add(int* __restrict__ out, const int* __restrict__ bsums, int n) {
  int i = blockIdx.x * 256 + threadIdx.x;
  if (i < n) out[i] += bsums[blockIdx.x];
}

// ---------- scatter: single-writer sub-segments, LDS cursors only ----------
__global__ __launch_bounds__(512) void escatter_kernel(
    const void* __restrict__ eidx, int E, int EP, int chunk,
    const int* __restrict__ flags, const int* __restrict__ base_g,
    u32* __restrict__ pairs, int nbuk) {
  __shared__ int cur[MAXBUK];
  int t = threadIdx.x, blk = blockIdx.x;
  if (t < nbuk) cur[t] = base_g[t * NBLK + blk];
  __syncthreads();
  int lo = blk * chunk, hi = min(lo + chunk, EP);
  int is64 = flags[0];
  for (int i = lo + t; i < hi; i += 512) {
    int s, d;
    if (i < E) { s = load_idx(eidx, i, is64); d = load_idx(eidx, E + i, is64); }
    else { s = d = i - E; }
    int pos = atomicAdd(&cur[d >> 8], 1);
    pairs[pos] = ((u32)(d & 255) << 24) | (u32)s;   // N < 2^24
  }
}

// ---------- per-bucket local sort: LDS hist+scan, write offs/ends/ssrc ----------
__global__ __launch_bounds__(256) void bfinal_kernel(
    const u32* __restrict__ pairs, const int* __restrict__ base_g,
    int* __restrict__ offs, int* __restrict__ ends, int* __restrict__ ssrc,
    int N, int EP, int nbuk) {
  int b = blockIdx.x, t = threadIdx.x;
  int nb0 = b << 8;
  __shared__ int cnt[256];
  __shared__ int cur[256];
  __shared__ int wsum[4];
  cnt[t] = 0;
  __syncthreads();
  int seg_start = base_g[b * NBLK];
  int seg_end = (b + 1 < nbuk) ? base_g[(b + 1) * NBLK] : EP;
  for (int i = seg_start + t; i < seg_end; i += 256) {
    atomicAdd(&cnt[pairs[i] >> 24], 1);
  }
  __syncthreads();
  int v = cnt[t];
  int lane = t & 63, w = t >> 6;
  int s = v;
  #pragma unroll
  for (int off = 1; off < 64; off <<= 1) {
    int u = __shfl_up(s, off);
    if (lane >= off) s += u;
  }
  if (lane == 63) wsum[w] = s;
  __syncthreads();
  int add = 0;
  for (int k = 0; k < w; ++k) add += wsum[k];
  int excl = s + add - v;
  cur[t] = excl;
  int node = nb0 + t;
  if (node < N) { offs[node] = seg_start + excl; ends[node] = seg_start + excl + v; }
  __syncthreads();
  for (int i = seg_start + t; i < seg_end; i += 256) {
    u32 p = pairs[i];
    int pos = atomicAdd(&cur[p >> 24], 1);
    ssrc[seg_start + pos] = (int)(p & 0xFFFFFFu);
  }
}

// ---------- layer-1 aggregation + ELU + layer-2 projection ----------
__global__ __launch_bounds__(256) void node1_kernel(
    const int* __restrict__ ssrc, const int* __restrict__ offs, const int* __restrict__ ends,
    const u16* __restrict__ h, const float* __restrict__ a_src, const float* __restrict__ a_dst,
    const float* __restrict__ b1, const float* __restrict__ W2,
    const float* __restrict__ att_s2, const float* __restrict__ att_d2,
    float* __restrict__ h2, float* __restrict__ as2, float* __restrict__ ad2, int nn) {
  int wid = threadIdx.x >> 6, lane = threadIdx.x & 63;
  int n = blockIdx.x * 4 + wid;
  if (n >= nn) return;
  int j = lane << 1;
  int hh = lane >> 3;
  float adst = a_dst[n * 8 + hh];
  int beg = offs[n], end = ends[n];   // deg >= 1 (self-loop)
  float acc0 = 0.f, acc1 = 0.f, dsum = 0.f;
  for (int base = beg; base < end; base += 8) {
    int s[8]; u32 v[8]; float ea[8];
    #pragma unroll
    for (int u = 0; u < 8; ++u) {
      int id = base + u;
      s[u] = ssrc[id < end ? id : end - 1];
    }
    #pragma unroll
    for (int u = 0; u < 8; ++u) {
      v[u]  = ((const u32*)(h + (size_t)s[u] * 128))[lane];
      ea[u] = a_src[s[u] * 8 + hh];
    }
    #pragma unroll
    for (int u = 0; u < 8; ++u) {
      float e = ea[u] + adst;
      e = (e < 0.f) ? 0.2f * e : e;
      float ee = (base + u < end) ? __expf(e) : 0.f;
      float h0 = __uint_as_float(v[u] << 16);
      float h1 = __uint_as_float(v[u] & 0xFFFF0000u);
      acc0 = fmaf(ee, h0, acc0);
      acc1 = fmaf(ee, h1, acc1);
      dsum += ee;
    }
  }
  float inv = 1.f / dsum;
  float o0 = acc0 * inv + b1[j];
  float o1 = acc1 * inv + b1[j + 1];
  o0 = (o0 > 0.f) ? o0 : expm1f(o0);   // ELU
  o1 = (o1 > 0.f) ? o1 : expm1f(o1);
  float p0 = o0 * W2[j * 2]     + o1 * W2[(j + 1) * 2];
  float p1 = o0 * W2[j * 2 + 1] + o1 * W2[(j + 1) * 2 + 1];
  #pragma unroll
  for (int m = 1; m < 64; m <<= 1) { p0 += __shfl_xor(p0, m); p1 += __shfl_xor(p1, m); }
  if (lane == 0) {
    h2[n * 2] = p0; h2[n * 2 + 1] = p1;
    as2[n] = p0 * att_s2[0] + p1 * att_s2[1];
    ad2[n] = p0 * att_d2[0] + p1 * att_d2[1];
  }
}

// ---------- layer-2 aggregation + graph mean-pool (8-lane group per node) ----------
__global__ __launch_bounds__(256) void node2_kernel(
    const int* __restrict__ ssrc, const int* __restrict__ offs, const int* __restrict__ ends,
    const float* __restrict__ h2, const float* __restrict__ as2, const float* __restrict__ ad2,
    const float* __restrict__ b2, const void* __restrict__ batch, const int* __restrict__ flags,
    float* __restrict__ pool, int nn) {
  __shared__ float psum[128];
  __shared__ float pcnt[64];
  int t = threadIdx.x;
  if (t < 128) psum[t] = 0.f;
  if (t < 64) pcnt[t] = 0.f;
  __syncthreads();
  int grp = t >> 3, lane8 = t & 7;    // 32 groups of 8 lanes
  int b64 = flags[1];
  int n = blockIdx.x * 32 + grp;
  if (n < nn) {
    float adst = ad2[n];
    int beg = offs[n], end = ends[n];
    float acc0 = 0.f, acc1 = 0.f, dsum = 0.f;
    for (int idx = beg + lane8; idx < end; idx += 8) {
      int s = ssrc[idx];
      float e = as2[s] + adst;
      e = (e < 0.f) ? 0.2f * e : e;
      float ee = __expf(e);
      float2 hv = *(const float2*)(h2 + (size_t)s * 2);
      acc0 = fmaf(ee, hv.x, acc0);
      acc1 = fmaf(ee, hv.y, acc1);
      dsum += ee;
    }
    #pragma unroll
    for (int m = 1; m < 8; m <<= 1) {
      acc0 += __shfl_xor(acc0, m);
      acc1 += __shfl_xor(acc1, m);
      dsum += __shfl_xor(dsum, m);
    }
    if (lane8 == 0) {
      float o0 = acc0 / dsum + b2[0];
      float o1 = acc1 / dsum + b2[1];
      int g = load_idx(batch, n, b64);
      atomicAdd(&psum[g * 2], o0);
      atomicAdd(&psum[g * 2 + 1], o1);
      atomicAdd(&pcnt[g], 1.f);
    }
  }
  __syncthreads();
  if (t < 64 && pcnt[t] > 0.f) {
    atomicAdd(&pool[t * 2], psum[t * 2]);
    atomicAdd(&pool[t * 2 + 1], psum[t * 2 + 1]);
    atomicAdd(&pool[128 + t], pcnt[t]);
  }
}

// ---------- mean + log_softmax ----------
__global__ void finalize_kernel(const float* __restrict__ pool, float* __restrict__ out) {
  int g = threadIdx.x;
  if (g < 64) {
    float c = fmaxf(pool[128 + g], 1.f);
    float p0 = pool[g * 2] / c, p1 = pool[g * 2 + 1] / c;
    float m = fmaxf(p0, p1);
    float lse = m + logf(expf(p0 - m) + expf(p1 - m));
    out[g * 2] = p0 - lse;
    out[g * 2 + 1] = p1 - lse;
  }
}

extern "C" void kernel_launch(void* const* d_in, const int* in_sizes, int n_in,
                              void* d_out, int out_size, void* d_ws, size_t ws_size,
                              hipStream_t stream) {
  const float* x        = (const float*)d_in[0];
  const void* eidx      = d_in[1];
  const void* batch     = d_in[2];
  const float* W1       = (const float*)d_in[3];
  const float* att_src1 = (const float*)d_in[4];
  const float* att_dst1 = (const float*)d_in[5];
  const float* b1       = (const float*)d_in[6];
  const float* W2       = (const float*)d_in[7];
  const float* att_src2 = (const float*)d_in[8];
  const float* att_dst2 = (const float*)d_in[9];
  const float* b2       = (const float*)d_in[10];
  float* out = (float*)d_out;

  int N = in_sizes[0] / 128;
  int E = in_sizes[1] / 2;
  int EP = E + N;
  int NBUK = (N + 255) >> 8;         // <= MAXBUK for N <= 131072
  int NC = NBUK * NBLK;
  int NB = (NC + 255) / 256;
  int chunk = (EP + NBLK - 1) / NBLK;

  char* ws = (char*)d_ws;
  size_t o = 0;
  auto alloc = [&](size_t bytes) -> void* {
    void* p = ws + o;
    o += (bytes + 255) & ~(size_t)255;
    return p;
  };
  u16*   h      = (u16*)alloc((size_t)N * 128 * 2);    // 25.6 MB bf16
  float* a_src1 = (float*)alloc((size_t)N * 8 * 4);
  float* a_dst1 = (float*)alloc((size_t)N * 8 * 4);
  int*   offs   = (int*)alloc((size_t)N * 4);
  int*   ends   = (int*)alloc((size_t)N * 4);
  int*   hist_g = (int*)alloc((size_t)NC * 4);         // 400 KB
  int*   base_g = (int*)alloc((size_t)NC * 4);
  int*   bsums  = (int*)alloc((size_t)(NB + 1) * 4);
  u32*   pairs  = (u32*)alloc((size_t)EP * 4);         // 6.8 MB packed
  int*   ssrc   = (int*)alloc((size_t)EP * 4);
  float* h2     = (float*)alloc((size_t)N * 2 * 4);
  float* as2    = (float*)alloc((size_t)N * 4);
  float* ad2    = (float*)alloc((size_t)N * 4);
  float* pool   = (float*)alloc(192 * 4);
  int*   flags  = (int*)alloc(2 * 4);

  detect_kernel<<<1, 64, 0, stream>>>(eidx, 2 * E, batch, N, flags);
  zero_kernel<<<1, 256, 0, stream>>>(pool);
  gemm1_kernel<<<(N + 63) / 64, 256, 0, stream>>>(x, W1, att_src1, att_dst1,
                                                  h, a_src1, a_dst1, N);
  ehist_kernel<<<NBLK, 512, 0, stream>>>(eidx, E, EP, chunk, flags, hist_g, NBUK);
  scan_blk<<<NB, 256, 0, stream>>>(hist_g, base_g, bsums, NC);
  scan_top<<<1, 1024, 0, stream>>>(bsums, NB);
  scan_add<<<NB, 256, 0, stream>>>(base_g, bsums, NC);
  escatter_kernel<<<NBLK, 512, 0, stream>>>(eidx, E, EP, chunk, flags, base_g, pairs, NBUK);
  bfinal_kernel<<<NBUK, 256, 0, stream>>>(pairs, base_g, offs, ends, ssrc, N, EP, NBUK);
  node1_kernel<<<(N + 3) / 4, 256, 0, stream>>>(ssrc, offs, ends, h, a_src1, a_dst1,
                                                b1, W2, att_src2, att_dst2,
                                                h2, as2, ad2, N);
  node2_kernel<<<(N + 31) / 32, 256, 0, stream>>>(ssrc, offs, ends, h2, as2, ad2,
                                                  b2, batch, flags, pool, N);
  finalize_kernel<<<1, 64, 0, stream>>>(pool, out);
}

// Round 6
// 244.904 us; speedup vs baseline: 2.3685x; 1.0490x over previous
//
#include <hip/hip_runtime.h>
#include <math.h>

typedef long long ll;
typedef unsigned int u32;
typedef unsigned short u16;

#define NBLK 256          // partition blocks
#define MAXBUK 512        // supports N <= 131072

__device__ __forceinline__ int load_idx(const void* p, int i, int is64) {
  return is64 ? (int)((const ll*)p)[i] : ((const int*)p)[i];
}

__device__ __forceinline__ u16 f2bf(float f) {
  u32 u = __float_as_uint(f);
  u += 0x7FFFu + ((u >> 16) & 1u);
  return (u16)(u >> 16);
}

// ---------- detect whether integer inputs are int64 or int32 ----------
__global__ void detect_kernel(const void* __restrict__ eidx, int ne,
                              const void* __restrict__ batch, int nb,
                              int* __restrict__ flags) {
  if (threadIdx.x == 0 && blockIdx.x == 0) {
    int e64 = 1;
    for (int k = 1; k <= 16; ++k) {
      int i = (int)((ll)k * (ne / 2 - 1) / 16);
      ll v = ((const ll*)eidx)[i];
      if (v < 0 || v >= (1LL << 31)) { e64 = 0; break; }
    }
    int b64 = 1;
    for (int k = 1; k <= 16; ++k) {
      int i = (int)((ll)k * (nb / 2 - 1) / 16);
      ll v = ((const ll*)batch)[i];
      if (v < 0 || v >= (1LL << 31)) { b64 = 0; break; }
    }
    flags[0] = e64; flags[1] = b64;
  }
}

// ---------- zero pool only (hist zeroed in-kernel) ----------
__global__ void zero_kernel(float* __restrict__ pool) {
  int i = threadIdx.x;
  if (i < 192) pool[i] = 0.f;
}

// ---------- K1: h = x @ W1 (f32 acc, bf16 store; fused a_src1/a_dst1) ----------
__global__ __launch_bounds__(256) void gemm1_kernel(
    const float* __restrict__ x, const float* __restrict__ W1,
    const float* __restrict__ att_src, const float* __restrict__ att_dst,
    u16* __restrict__ h, float* __restrict__ a_src, float* __restrict__ a_dst,
    int nn) {
  __shared__ float4 Ws[128][32];   // 64 KB
  __shared__ float xs[32][128];    // 16 KB
  int t = threadIdx.x;
  const float4* W4 = (const float4*)W1;
  #pragma unroll
  for (int i = 0; i < 16; ++i) {
    int f = t + i * 256;           // 4096 float4s
    Ws[f >> 5][f & 31] = W4[f];
  }
  int q = t & 31, p = t >> 5;
  int n0 = blockIdx.x * 64;
  const float4 as4 = ((const float4*)att_src)[q];
  const float4 ad4 = ((const float4*)att_dst)[q];
  for (int g = 0; g < 64; g += 32) {
    __syncthreads();
    #pragma unroll
    for (int i = 0; i < 4; ++i) {
      int f = t + i * 256;         // 1024 float4s = 32 rows
      int node = f >> 5, c4 = f & 31;
      int gn = n0 + g + node;
      float4 v = make_float4(0.f, 0.f, 0.f, 0.f);
      if (gn < nn) v = ((const float4*)x)[(size_t)gn * 32 + c4];
      *(float4*)&xs[node][c4 << 2] = v;
    }
    __syncthreads();
    float4 acc[4];
    #pragma unroll
    for (int r = 0; r < 4; ++r) acc[r] = make_float4(0.f, 0.f, 0.f, 0.f);
    #pragma unroll 4
    for (int k = 0; k < 128; ++k) {
      float4 w = Ws[k][q];
      #pragma unroll
      for (int r = 0; r < 4; ++r) {
        float xv = xs[p + r * 8][k];
        acc[r].x = fmaf(xv, w.x, acc[r].x);
        acc[r].y = fmaf(xv, w.y, acc[r].y);
        acc[r].z = fmaf(xv, w.z, acc[r].z);
        acc[r].w = fmaf(xv, w.w, acc[r].w);
      }
    }
    int head = q >> 2;
    #pragma unroll
    for (int r = 0; r < 4; ++r) {
      int n = n0 + g + p + r * 8;
      float s = acc[r].x*as4.x + acc[r].y*as4.y + acc[r].z*as4.z + acc[r].w*as4.w;
      float d = acc[r].x*ad4.x + acc[r].y*ad4.y + acc[r].z*ad4.z + acc[r].w*ad4.w;
      s += __shfl_xor(s, 1); s += __shfl_xor(s, 2);
      d += __shfl_xor(d, 1); d += __shfl_xor(d, 2);
      if (n < nn) {
        uint2 pk;
        pk.x = (u32)f2bf(acc[r].x) | ((u32)f2bf(acc[r].y) << 16);
        pk.y = (u32)f2bf(acc[r].z) | ((u32)f2bf(acc[r].w) << 16);
        ((uint2*)(h + (size_t)n * 128))[q] = pk;
        if ((q & 3) == 0) { a_src[n * 8 + head] = s; a_dst[n * 8 + head] = d; }
      }
    }
  }
}

// ---------- per-block LDS histogram of dst buckets (no global atomics) ----------
__global__ __launch_bounds__(512) void ehist_kernel(
    const void* __restrict__ eidx, int E, int EP, int chunk,
    const int* __restrict__ flags, int* __restrict__ hist_g, int nbuk) {
  __shared__ int cnt[MAXBUK];
  int t = threadIdx.x, blk = blockIdx.x;
  if (t < MAXBUK) cnt[t] = 0;
  __syncthreads();
  int lo = blk * chunk, hi = min(lo + chunk, EP);
  int is64 = flags[0];
  for (int i = lo + t; i < hi; i += 512) {
    int d = (i < E) ? load_idx(eidx, E + i, is64) : (i - E);
    atomicAdd(&cnt[d >> 8], 1);
  }
  __syncthreads();
  if (t < nbuk) hist_g[t * NBLK + blk] = cnt[t];
}

// ---------- two-level exclusive scan over nbuk*NBLK counters ----------
__global__ __launch_bounds__(256) void scan_blk(const int* __restrict__ in,
                                                int* __restrict__ out,
                                                int* __restrict__ bsums, int n) {
  int t = threadIdx.x;
  int i = blockIdx.x * 256 + t;
  int v = (i < n) ? in[i] : 0;
  int lane = t & 63, w = t >> 6;
  int s = v;
  #pragma unroll
  for (int off = 1; off < 64; off <<= 1) {
    int u = __shfl_up(s, off);
    if (lane >= off) s += u;
  }
  __shared__ int wsum[4];
  if (lane == 63) wsum[w] = s;
  __syncthreads();
  int add = 0;
  for (int k = 0; k < w; ++k) add += wsum[k];
  int incl = s + add;
  if (i < n) out[i] = incl - v;
  if (t == 255) bsums[blockIdx.x] = incl;
}

__global__ __launch_bounds__(1024) void scan_top(int* __restrict__ bsums, int nb) {
  int t = threadIdx.x;
  int v = (t < nb) ? bsums[t] : 0;
  int lane = t & 63, w = t >> 6;
  int s = v;
  #pragma unroll
  for (int off = 1; off < 64; off <<= 1) {
    int u = __shfl_up(s, off);
    if (lane >= off) s += u;
  }
  __shared__ int ws[16];
  if (lane == 63) ws[w] = s;
  __syncthreads();
  int add = 0;
  for (int k = 0; k < w; ++k) add += ws[k];
  if (t < nb) bsums[t] = s + add - v;
}

__global__ void scan_add(int* __restrict__ out, const int* __restrict__ bsums, int n) {
  int i = blockIdx.x * 256 + threadIdx.x;
  if (i < n) out[i] += bsums[blockIdx.x];
}

// ---------- scatter: single-writer sub-segments, LDS cursors only ----------
__global__ __launch_bounds__(512) void escatter_kernel(
    const void* __restrict__ eidx, int E, int EP, int chunk,
    const int* __restrict__ flags, const int* __restrict__ base_g,
    u32* __restrict__ pairs, int nbuk) {
  __shared__ int cur[MAXBUK];
  int t = threadIdx.x, blk = blockIdx.x;
  if (t < nbuk) cur[t] = base_g[t * NBLK + blk];
  __syncthreads();
  int lo = blk * chunk, hi = min(lo + chunk, EP);
  int is64 = flags[0];
  for (int i = lo + t; i < hi; i += 512) {
    int s, d;
    if (i < E) { s = load_idx(eidx, i, is64); d = load_idx(eidx, E + i, is64); }
    else { s = d = i - E; }
    int pos = atomicAdd(&cur[d >> 8], 1);
    pairs[pos] = ((u32)(d & 255) << 24) | (u32)s;   // N < 2^24
  }
}

// ---------- per-bucket local sort: LDS hist+scan, write offs/ends/ssrc ----------
__global__ __launch_bounds__(256) void bfinal_kernel(
    const u32* __restrict__ pairs, const int* __restrict__ base_g,
    int* __restrict__ offs, int* __restrict__ ends, int* __restrict__ ssrc,
    int N, int EP, int nbuk) {
  int b = blockIdx.x, t = threadIdx.x;
  int nb0 = b << 8;
  __shared__ int cnt[256];
  __shared__ int cur[256];
  __shared__ int wsum[4];
  cnt[t] = 0;
  __syncthreads();
  int seg_start = base_g[b * NBLK];
  int seg_end = (b + 1 < nbuk) ? base_g[(b + 1) * NBLK] : EP;
  for (int i = seg_start + t; i < seg_end; i += 256) {
    atomicAdd(&cnt[pairs[i] >> 24], 1);
  }
  __syncthreads();
  int v = cnt[t];
  int lane = t & 63, w = t >> 6;
  int s = v;
  #pragma unroll
  for (int off = 1; off < 64; off <<= 1) {
    int u = __shfl_up(s, off);
    if (lane >= off) s += u;
  }
  if (lane == 63) wsum[w] = s;
  __syncthreads();
  int add = 0;
  for (int k = 0; k < w; ++k) add += wsum[k];
  int excl = s + add - v;
  cur[t] = excl;
  int node = nb0 + t;
  if (node < N) { offs[node] = seg_start + excl; ends[node] = seg_start + excl + v; }
  __syncthreads();
  for (int i = seg_start + t; i < seg_end; i += 256) {
    u32 p = pairs[i];
    int pos = atomicAdd(&cur[p >> 24], 1);
    ssrc[seg_start + pos] = (int)(p & 0xFFFFFFu);
  }
}

// ---------- layer-1 aggregation + ELU + layer-2 projection ----------
// 16 lanes per node, 4 nodes per wave; lane owns 8 dims (uint4 of bf16),
// head = lg>>1 so the softmax denominator is lane-local.
__global__ __launch_bounds__(256) void node1_kernel(
    const int* __restrict__ ssrc, const int* __restrict__ offs, const int* __restrict__ ends,
    const u16* __restrict__ h, const float* __restrict__ a_src, const float* __restrict__ a_dst,
    const float* __restrict__ b1, const float* __restrict__ W2,
    const float* __restrict__ att_s2, const float* __restrict__ att_d2,
    float* __restrict__ h2, float* __restrict__ as2, float* __restrict__ ad2, int nn) {
  int t = threadIdx.x;
  int wid = t >> 6, lane = t & 63;
  int grp = lane >> 4, lg = lane & 15;      // 4 node-groups of 16 lanes
  int n = blockIdx.x * 16 + wid * 4 + grp;
  bool nvalid = (n < nn);
  int nc = nvalid ? n : (nn - 1);
  int hh = lg >> 1;                          // head for this lane's 8 dims
  float adst = a_dst[nc * 8 + hh];
  int beg = offs[nc], end = ends[nc];
  int deg = nvalid ? (end - beg) : 0;
  int maxd = deg;
  maxd = max(maxd, __shfl_xor(maxd, 16));
  maxd = max(maxd, __shfl_xor(maxd, 32));    // wave-wide max degree
  float acc[8];
  #pragma unroll
  for (int k = 0; k < 8; ++k) acc[k] = 0.f;
  float dsum = 0.f;
  const u32* h32 = (const u32*)h;
  for (int it = 0; it < maxd; it += 4) {
    int s4[4]; float ea4[4]; uint4 v4[4];
    #pragma unroll
    for (int u = 0; u < 4; ++u) {
      int id = beg + it + u;
      s4[u] = ssrc[id < end ? id : end - 1];
    }
    #pragma unroll
    for (int u = 0; u < 4; ++u) {
      v4[u]  = *(const uint4*)(h32 + s4[u] * 64 + lg * 4);  // 32-bit index math
      ea4[u] = a_src[s4[u] * 8 + hh];
    }
    #pragma unroll
    for (int u = 0; u < 4; ++u) {
      float e = ea4[u] + adst;
      e = fmaxf(e, 0.2f * e);                 // leaky_relu
      float ee = (it + u < deg) ? __expf(e) : 0.f;
      dsum += ee;
      acc[0] = fmaf(ee, __uint_as_float(v4[u].x << 16),          acc[0]);
      acc[1] = fmaf(ee, __uint_as_float(v4[u].x & 0xFFFF0000u),  acc[1]);
      acc[2] = fmaf(ee, __uint_as_float(v4[u].y << 16),          acc[2]);
      acc[3] = fmaf(ee, __uint_as_float(v4[u].y & 0xFFFF0000u),  acc[3]);
      acc[4] = fmaf(ee, __uint_as_float(v4[u].z << 16),          acc[4]);
      acc[5] = fmaf(ee, __uint_as_float(v4[u].z & 0xFFFF0000u),  acc[5]);
      acc[6] = fmaf(ee, __uint_as_float(v4[u].w << 16),          acc[6]);
      acc[7] = fmaf(ee, __uint_as_float(v4[u].w & 0xFFFF0000u),  acc[7]);
    }
  }
  float inv = 1.f / dsum;                     // lane-local denominator
  float p0 = 0.f, p1 = 0.f;
  #pragma unroll
  for (int k = 0; k < 8; ++k) {
    int j = lg * 8 + k;
    float o = acc[k] * inv + b1[j];
    o = (o > 0.f) ? o : expm1f(o);            // ELU
    p0 = fmaf(o, W2[j * 2],     p0);
    p1 = fmaf(o, W2[j * 2 + 1], p1);
  }
  #pragma unroll
  for (int m = 1; m < 16; m <<= 1) { p0 += __shfl_xor(p0, m); p1 += __shfl_xor(p1, m); }
  if (nvalid && lg == 0) {
    h2[n * 2] = p0; h2[n * 2 + 1] = p1;
    as2[n] = p0 * att_s2[0] + p1 * att_s2[1];
    ad2[n] = p0 * att_d2[0] + p1 * att_d2[1];
  }
}

// ---------- layer-2 aggregation + graph mean-pool (8-lane group per node) ----------
__global__ __launch_bounds__(256) void node2_kernel(
    const int* __restrict__ ssrc, const int* __restrict__ offs, const int* __restrict__ ends,
    const float* __restrict__ h2, const float* __restrict__ as2, const float* __restrict__ ad2,
    const float* __restrict__ b2, const void* __restrict__ batch, const int* __restrict__ flags,
    float* __restrict__ pool, int nn) {
  __shared__ float psum[128];
  __shared__ float pcnt[64];
  int t = threadIdx.x;
  if (t < 128) psum[t] = 0.f;
  if (t < 64) pcnt[t] = 0.f;
  __syncthreads();
  int grp = t >> 3, lane8 = t & 7;    // 32 groups of 8 lanes
  int b64 = flags[1];
  int n = blockIdx.x * 32 + grp;
  if (n < nn) {
    float adst = ad2[n];
    int beg = offs[n], end = ends[n];
    float acc0 = 0.f, acc1 = 0.f, dsum = 0.f;
    for (int idx = beg + lane8; idx < end; idx += 8) {
      int s = ssrc[idx];
      float e = as2[s] + adst;
      e = (e < 0.f) ? 0.2f * e : e;
      float ee = __expf(e);
      float2 hv = *(const float2*)(h2 + (size_t)s * 2);
      acc0 = fmaf(ee, hv.x, acc0);
      acc1 = fmaf(ee, hv.y, acc1);
      dsum += ee;
    }
    #pragma unroll
    for (int m = 1; m < 8; m <<= 1) {
      acc0 += __shfl_xor(acc0, m);
      acc1 += __shfl_xor(acc1, m);
      dsum += __shfl_xor(dsum, m);
    }
    if (lane8 == 0) {
      float o0 = acc0 / dsum + b2[0];
      float o1 = acc1 / dsum + b2[1];
      int g = load_idx(batch, n, b64);
      atomicAdd(&psum[g * 2], o0);
      atomicAdd(&psum[g * 2 + 1], o1);
      atomicAdd(&pcnt[g], 1.f);
    }
  }
  __syncthreads();
  if (t < 64 && pcnt[t] > 0.f) {
    atomicAdd(&pool[t * 2], psum[t * 2]);
    atomicAdd(&pool[t * 2 + 1], psum[t * 2 + 1]);
    atomicAdd(&pool[128 + t], pcnt[t]);
  }
}

// ---------- mean + log_softmax ----------
__global__ void finalize_kernel(const float* __restrict__ pool, float* __restrict__ out) {
  int g = threadIdx.x;
  if (g < 64) {
    float c = fmaxf(pool[128 + g], 1.f);
    float p0 = pool[g * 2] / c, p1 = pool[g * 2 + 1] / c;
    float m = fmaxf(p0, p1);
    float lse = m + logf(expf(p0 - m) + expf(p1 - m));
    out[g * 2] = p0 - lse;
    out[g * 2 + 1] = p1 - lse;
  }
}

extern "C" void kernel_launch(void* const* d_in, const int* in_sizes, int n_in,
                              void* d_out, int out_size, void* d_ws, size_t ws_size,
                              hipStream_t stream) {
  const float* x        = (const float*)d_in[0];
  const void* eidx      = d_in[1];
  const void* batch     = d_in[2];
  const float* W1       = (const float*)d_in[3];
  const float* att_src1 = (const float*)d_in[4];
  const float* att_dst1 = (const float*)d_in[5];
  const float* b1       = (const float*)d_in[6];
  const float* W2       = (const float*)d_in[7];
  const float* att_src2 = (const float*)d_in[8];
  const float* att_dst2 = (const float*)d_in[9];
  const float* b2       = (const float*)d_in[10];
  float* out = (float*)d_out;

  int N = in_sizes[0] / 128;
  int E = in_sizes[1] / 2;
  int EP = E + N;
  int NBUK = (N + 255) >> 8;         // <= MAXBUK for N <= 131072
  int NC = NBUK * NBLK;
  int NB = (NC + 255) / 256;
  int chunk = (EP + NBLK - 1) / NBLK;

  char* ws = (char*)d_ws;
  size_t o = 0;
  auto alloc = [&](size_t bytes) -> void* {
    void* p = ws + o;
    o += (bytes + 255) & ~(size_t)255;
    return p;
  };
  u16*   h      = (u16*)alloc((size_t)N * 128 * 2);    // 25.6 MB bf16
  float* a_src1 = (float*)alloc((size_t)N * 8 * 4);
  float* a_dst1 = (float*)alloc((size_t)N * 8 * 4);
  int*   offs   = (int*)alloc((size_t)N * 4);
  int*   ends   = (int*)alloc((size_t)N * 4);
  int*   hist_g = (int*)alloc((size_t)NC * 4);         // 400 KB
  int*   base_g = (int*)alloc((size_t)NC * 4);
  int*   bsums  = (int*)alloc((size_t)(NB + 1) * 4);
  u32*   pairs  = (u32*)alloc((size_t)EP * 4);         // 6.8 MB packed
  int*   ssrc   = (int*)alloc((size_t)EP * 4);
  float* h2     = (float*)alloc((size_t)N * 2 * 4);
  float* as2    = (float*)alloc((size_t)N * 4);
  float* ad2    = (float*)alloc((size_t)N * 4);
  float* pool   = (float*)alloc(192 * 4);
  int*   flags  = (int*)alloc(2 * 4);

  detect_kernel<<<1, 64, 0, stream>>>(eidx, 2 * E, batch, N, flags);
  zero_kernel<<<1, 256, 0, stream>>>(pool);
  gemm1_kernel<<<(N + 63) / 64, 256, 0, stream>>>(x, W1, att_src1, att_dst1,
                                                  h, a_src1, a_dst1, N);
  ehist_kernel<<<NBLK, 512, 0, stream>>>(eidx, E, EP, chunk, flags, hist_g, NBUK);
  scan_blk<<<NB, 256, 0, stream>>>(hist_g, base_g, bsums, NC);
  scan_top<<<1, 1024, 0, stream>>>(bsums, NB);
  scan_add<<<NB, 256, 0, stream>>>(base_g, bsums, NC);
  escatter_kernel<<<NBLK, 512, 0, stream>>>(eidx, E, EP, chunk, flags, base_g, pairs, NBUK);
  bfinal_kernel<<<NBUK, 256, 0, stream>>>(pairs, base_g, offs, ends, ssrc, N, EP, NBUK);
  node1_kernel<<<(N + 15) / 16, 256, 0, stream>>>(ssrc, offs, ends, h, a_src1, a_dst1,
                                                  b1, W2, att_src2, att_dst2,
                                                  h2, as2, ad2, N);
  node2_kernel<<<(N + 31) / 32, 256, 0, stream>>>(ssrc, offs, ends, h2, as2, ad2,
                                                  b2, batch, flags, pool, N);
  finalize_kernel<<<1, 64, 0, stream>>>(pool, out);
}

// Round 7
// 214.007 us; speedup vs baseline: 2.7104x; 1.1444x over previous
//
#include <hip/hip_runtime.h>
#include <math.h>

typedef long long ll;
typedef unsigned int u32;
typedef unsigned short u16;
typedef __attribute__((ext_vector_type(8))) short short8;
typedef __attribute__((ext_vector_type(4))) float f32x4;

#define NBLK 256          // partition blocks
#define MAXBUK 512        // supports N <= 131072

__device__ __forceinline__ int load_idx(const void* p, int i, int is64) {
  return is64 ? (int)((const ll*)p)[i] : ((const int*)p)[i];
}

__device__ __forceinline__ u16 f2bf(float f) {
  u32 u = __float_as_uint(f);
  u += 0x7FFFu + ((u >> 16) & 1u);
  return (u16)(u >> 16);
}

// ---------- detect whether integer inputs are int64 or int32 ----------
__global__ void detect_kernel(const void* __restrict__ eidx, int ne,
                              const void* __restrict__ batch, int nb,
                              int* __restrict__ flags) {
  if (threadIdx.x == 0 && blockIdx.x == 0) {
    int e64 = 1;
    for (int k = 1; k <= 16; ++k) {
      int i = (int)((ll)k * (ne / 2 - 1) / 16);
      ll v = ((const ll*)eidx)[i];
      if (v < 0 || v >= (1LL << 31)) { e64 = 0; break; }
    }
    int b64 = 1;
    for (int k = 1; k <= 16; ++k) {
      int i = (int)((ll)k * (nb / 2 - 1) / 16);
      ll v = ((const ll*)batch)[i];
      if (v < 0 || v >= (1LL << 31)) { b64 = 0; break; }
    }
    flags[0] = e64; flags[1] = b64;
  }
}

// ---------- zero pool only (hist zeroed in-kernel) ----------
__global__ void zero_kernel(float* __restrict__ pool) {
  int i = threadIdx.x;
  if (i < 192) pool[i] = 0.f;
}

// ---------- K1: h = x @ W1 via MFMA bf16 (f32 acc; fused a_src1/a_dst1) ----------
// Block: 256 thr = 4 waves, 64 nodes. LDS: xs[64][136]u16 + Wt[128][136]u16,
// epilogue overlays hs[64][132]f32 on the same region (after barrier).
__global__ __launch_bounds__(256) void gemm1_kernel(
    const float* __restrict__ x, const float* __restrict__ W1,
    const float* __restrict__ att_src, const float* __restrict__ att_dst,
    u16* __restrict__ h, float* __restrict__ a_src, float* __restrict__ a_dst,
    int nn) {
  __shared__ __align__(16) char smem[64 * 136 * 2 + 128 * 136 * 2];  // 52224 B
  u16* xs = (u16*)smem;                       // [64][136]
  u16* Wt = (u16*)(smem + 64 * 136 * 2);      // [128][136]  Wt[j][k]
  float* hs = (float*)smem;                   // [64][132]   (overlay)
  int t = threadIdx.x;
  int n0 = blockIdx.x * 64;

  // stage Wt = W1^T in bf16 (W1 is [k=128][j=128])
  #pragma unroll 4
  for (int p = 0; p < 64; ++p) {
    int i = t + p * 256;          // 16384 elements
    int k = i >> 7, j = i & 127;
    u16 w = f2bf(W1[i]);
    Wt[j * 136 + k] = w;
  }
  // stage x tile as bf16
  #pragma unroll
  for (int p = 0; p < 4; ++p) {
    int row = p * 16 + (t >> 4);
    int c = t & 15;               // 8-float chunk
    int gn = n0 + row;
    uint4 pk = make_uint4(0u, 0u, 0u, 0u);
    if (gn < nn) {
      const float4* xp = (const float4*)(x + (size_t)gn * 128 + c * 8);
      float4 f0 = xp[0], f1 = xp[1];
      pk.x = (u32)f2bf(f0.x) | ((u32)f2bf(f0.y) << 16);
      pk.y = (u32)f2bf(f0.z) | ((u32)f2bf(f0.w) << 16);
      pk.z = (u32)f2bf(f1.x) | ((u32)f2bf(f1.y) << 16);
      pk.w = (u32)f2bf(f1.z) | ((u32)f2bf(f1.w) << 16);
    }
    *(uint4*)&xs[row * 136 + c * 8] = pk;
  }
  __syncthreads();

  int lane = t & 63, wid = t >> 6;
  int lrow = lane & 15, lq = lane >> 4;
  // A fragments: lane holds A[row=l&15][k=(l>>4)*8 .. +7]
  short8 a[4];
  #pragma unroll
  for (int ks = 0; ks < 4; ++ks) {
    int row = wid * 16 + lrow;
    a[ks] = *(const short8*)&xs[row * 136 + ks * 32 + lq * 8];
  }
  f32x4 c[8];
  #pragma unroll
  for (int jt = 0; jt < 8; ++jt) c[jt] = (f32x4)(0.f);
  #pragma unroll
  for (int jt = 0; jt < 8; ++jt) {
    int j = jt * 16 + lrow;
    #pragma unroll
    for (int ks = 0; ks < 4; ++ks) {
      short8 b = *(const short8*)&Wt[j * 136 + ks * 32 + lq * 8];
      c[jt] = __builtin_amdgcn_mfma_f32_16x16x32_bf16(a[ks], b, c[jt], 0, 0, 0);
    }
  }
  __syncthreads();   // all xs/Wt reads done; reuse LDS as hs

  // C layout: col = lane&15, row = (lane>>4)*4 + reg
  #pragma unroll
  for (int jt = 0; jt < 8; ++jt) {
    #pragma unroll
    for (int r = 0; r < 4; ++r) {
      hs[(wid * 16 + lq * 4 + r) * 132 + jt * 16 + lrow] = c[jt][r];
    }
  }
  __syncthreads();

  // epilogue (proven pattern): float4 read, 4-lane reduce, packed store
  int q = t & 31, p = t >> 5;
  const float4 as4 = ((const float4*)att_src)[q];
  const float4 ad4 = ((const float4*)att_dst)[q];
  int head = q >> 2;
  #pragma unroll
  for (int rr = 0; rr < 8; ++rr) {
    int row = rr * 8 + p;
    int n = n0 + row;
    float4 v = *(const float4*)&hs[row * 132 + q * 4];
    float s = v.x * as4.x + v.y * as4.y + v.z * as4.z + v.w * as4.w;
    float d = v.x * ad4.x + v.y * ad4.y + v.z * ad4.z + v.w * ad4.w;
    s += __shfl_xor(s, 1); s += __shfl_xor(s, 2);
    d += __shfl_xor(d, 1); d += __shfl_xor(d, 2);
    if (n < nn) {
      uint2 pk;
      pk.x = (u32)f2bf(v.x) | ((u32)f2bf(v.y) << 16);
      pk.y = (u32)f2bf(v.z) | ((u32)f2bf(v.w) << 16);
      ((uint2*)(h + (size_t)n * 128))[q] = pk;
      if ((q & 3) == 0) { a_src[n * 8 + head] = s; a_dst[n * 8 + head] = d; }
    }
  }
}

// ---------- per-block LDS histogram of dst buckets (no global atomics) ----------
__global__ __launch_bounds__(512) void ehist_kernel(
    const void* __restrict__ eidx, int E, int EP, int chunk,
    const int* __restrict__ flags, int* __restrict__ hist_g, int nbuk) {
  __shared__ int cnt[MAXBUK];
  int t = threadIdx.x, blk = blockIdx.x;
  if (t < MAXBUK) cnt[t] = 0;
  __syncthreads();
  int lo = blk * chunk, hi = min(lo + chunk, EP);
  int is64 = flags[0];
  for (int i = lo + t; i < hi; i += 512) {
    int d = (i < E) ? load_idx(eidx, E + i, is64) : (i - E);
    atomicAdd(&cnt[d >> 8], 1);
  }
  __syncthreads();
  if (t < nbuk) hist_g[t * NBLK + blk] = cnt[t];
}

// ---------- two-level exclusive scan over nbuk*NBLK counters ----------
__global__ __launch_bounds__(256) void scan_blk(const int* __restrict__ in,
                                                int* __restrict__ out,
                                                int* __restrict__ bsums, int n) {
  int t = threadIdx.x;
  int i = blockIdx.x * 256 + t;
  int v = (i < n) ? in[i] : 0;
  int lane = t & 63, w = t >> 6;
  int s = v;
  #pragma unroll
  for (int off = 1; off < 64; off <<= 1) {
    int u = __shfl_up(s, off);
    if (lane >= off) s += u;
  }
  __shared__ int wsum[4];
  if (lane == 63) wsum[w] = s;
  __syncthreads();
  int add = 0;
  for (int k = 0; k < w; ++k) add += wsum[k];
  int incl = s + add;
  if (i < n) out[i] = incl - v;
  if (t == 255) bsums[blockIdx.x] = incl;
}

__global__ __launch_bounds__(1024) void scan_top(int* __restrict__ bsums, int nb) {
  int t = threadIdx.x;
  int v = (t < nb) ? bsums[t] : 0;
  int lane = t & 63, w = t >> 6;
  int s = v;
  #pragma unroll
  for (int off = 1; off < 64; off <<= 1) {
    int u = __shfl_up(s, off);
    if (lane >= off) s += u;
  }
  __shared__ int ws[16];
  if (lane == 63) ws[w] = s;
  __syncthreads();
  int add = 0;
  for (int k = 0; k < w; ++k) add += ws[k];
  if (t < nb) bsums[t] = s + add - v;
}

__global__ void scan_add(int* __restrict__ out, const int* __restrict__ bsums, int n) {
  int i = blockIdx.x * 256 + threadIdx.x;
  if (i < n) out[i] += bsums[blockIdx.x];
}

// ---------- scatter: single-writer sub-segments, LDS cursors only ----------
__global__ __launch_bounds__(512) void escatter_kernel(
    const void* __restrict__ eidx, int E, int EP, int chunk,
    const int* __restrict__ flags, const int* __restrict__ base_g,
    u32* __restrict__ pairs, int nbuk) {
  __shared__ int cur[MAXBUK];
  int t = threadIdx.x, blk = blockIdx.x;
  if (t < nbuk) cur[t] = base_g[t * NBLK + blk];
  __syncthreads();
  int lo = blk * chunk, hi = min(lo + chunk, EP);
  int is64 = flags[0];
  for (int i = lo + t; i < hi; i += 512) {
    int s, d;
    if (i < E) { s = load_idx(eidx, i, is64); d = load_idx(eidx, E + i, is64); }
    else { s = d = i - E; }
    int pos = atomicAdd(&cur[d >> 8], 1);
    pairs[pos] = ((u32)(d & 255) << 24) | (u32)s;   // N < 2^24
  }
}

// ---------- per-bucket local sort: LDS hist+scan, write offs/ends/ssrc ----------
__global__ __launch_bounds__(256) void bfinal_kernel(
    const u32* __restrict__ pairs, const int* __restrict__ base_g,
    int* __restrict__ offs, int* __restrict__ ends, int* __restrict__ ssrc,
    int N, int EP, int nbuk) {
  int b = blockIdx.x, t = threadIdx.x;
  int nb0 = b << 8;
  __shared__ int cnt[256];
  __shared__ int cur[256];
  __shared__ int wsum[4];
  cnt[t] = 0;
  __syncthreads();
  int seg_start = base_g[b * NBLK];
  int seg_end = (b + 1 < nbuk) ? base_g[(b + 1) * NBLK] : EP;
  for (int i = seg_start + t; i < seg_end; i += 256) {
    atomicAdd(&cnt[pairs[i] >> 24], 1);
  }
  __syncthreads();
  int v = cnt[t];
  int lane = t & 63, w = t >> 6;
  int s = v;
  #pragma unroll
  for (int off = 1; off < 64; off <<= 1) {
    int u = __shfl_up(s, off);
    if (lane >= off) s += u;
  }
  if (lane == 63) wsum[w] = s;
  __syncthreads();
  int add = 0;
  for (int k = 0; k < w; ++k) add += wsum[k];
  int excl = s + add - v;
  cur[t] = excl;
  int node = nb0 + t;
  if (node < N) { offs[node] = seg_start + excl; ends[node] = seg_start + excl + v; }
  __syncthreads();
  for (int i = seg_start + t; i < seg_end; i += 256) {
    u32 p = pairs[i];
    int pos = atomicAdd(&cur[p >> 24], 1);
    ssrc[seg_start + pos] = (int)(p & 0xFFFFFFu);
  }
}

// ---------- layer-1 aggregation + ELU + layer-2 projection ----------
// 16 lanes per node, 4 nodes per wave; lane owns 8 dims; ssrc prefetched
// one step ahead to break the ssrc->gather dependency chain.
__global__ __launch_bounds__(256) void node1_kernel(
    const int* __restrict__ ssrc, const int* __restrict__ offs, const int* __restrict__ ends,
    const u16* __restrict__ h, const float* __restrict__ a_src, const float* __restrict__ a_dst,
    const float* __restrict__ b1, const float* __restrict__ W2,
    const float* __restrict__ att_s2, const float* __restrict__ att_d2,
    float* __restrict__ h2, float* __restrict__ as2, float* __restrict__ ad2, int nn) {
  int t = threadIdx.x;
  int wid = t >> 6, lane = t & 63;
  int grp = lane >> 4, lg = lane & 15;      // 4 node-groups of 16 lanes
  int n = blockIdx.x * 16 + wid * 4 + grp;
  bool nvalid = (n < nn);
  int nc = nvalid ? n : (nn - 1);
  int hh = lg >> 1;                          // head for this lane's 8 dims
  float adst = a_dst[nc * 8 + hh];
  int beg = offs[nc], end = ends[nc];
  int deg = nvalid ? (end - beg) : 0;
  int maxd = deg;
  maxd = max(maxd, __shfl_xor(maxd, 16));
  maxd = max(maxd, __shfl_xor(maxd, 32));    // wave-wide max degree
  float acc[8];
  #pragma unroll
  for (int k = 0; k < 8; ++k) acc[k] = 0.f;
  float dsum = 0.f;
  const u32* h32 = (const u32*)h;

  auto ld4 = [&](int* s4, int it0) {
    #pragma unroll
    for (int u = 0; u < 4; ++u) {
      int id = beg + it0 + u;
      s4[u] = ssrc[id < end ? id : end - 1];
    }
  };
  auto step = [&](const int* s4, int it0) {
    float ea4[4]; uint4 v4[4];
    #pragma unroll
    for (int u = 0; u < 4; ++u) {
      v4[u]  = *(const uint4*)(h32 + s4[u] * 64 + lg * 4);
      ea4[u] = a_src[s4[u] * 8 + hh];
    }
    #pragma unroll
    for (int u = 0; u < 4; ++u) {
      float e = ea4[u] + adst;
      e = fmaxf(e, 0.2f * e);                 // leaky_relu
      float ee = (it0 + u < deg) ? __expf(e) : 0.f;
      dsum += ee;
      acc[0] = fmaf(ee, __uint_as_float(v4[u].x << 16),          acc[0]);
      acc[1] = fmaf(ee, __uint_as_float(v4[u].x & 0xFFFF0000u),  acc[1]);
      acc[2] = fmaf(ee, __uint_as_float(v4[u].y << 16),          acc[2]);
      acc[3] = fmaf(ee, __uint_as_float(v4[u].y & 0xFFFF0000u),  acc[3]);
      acc[4] = fmaf(ee, __uint_as_float(v4[u].z << 16),          acc[4]);
      acc[5] = fmaf(ee, __uint_as_float(v4[u].z & 0xFFFF0000u),  acc[5]);
      acc[6] = fmaf(ee, __uint_as_float(v4[u].w << 16),          acc[6]);
      acc[7] = fmaf(ee, __uint_as_float(v4[u].w & 0xFFFF0000u),  acc[7]);
    }
  };

  if (maxd > 0) {
    int sa[4], sb[4];
    ld4(sa, 0);
    for (int it = 0; it < maxd; it += 8) {
      ld4(sb, it + 4);         // prefetch next 4 indices (independent)
      step(sa, it);
      ld4(sa, it + 8);
      step(sb, it + 4);
    }
  }

  float inv = 1.f / dsum;                     // lane-local denominator
  float p0 = 0.f, p1 = 0.f;
  #pragma unroll
  for (int k = 0; k < 8; ++k) {
    int j = lg * 8 + k;
    float o = acc[k] * inv + b1[j];
    o = (o > 0.f) ? o : expm1f(o);            // ELU
    p0 = fmaf(o, W2[j * 2],     p0);
    p1 = fmaf(o, W2[j * 2 + 1], p1);
  }
  #pragma unroll
  for (int m = 1; m < 16; m <<= 1) { p0 += __shfl_xor(p0, m); p1 += __shfl_xor(p1, m); }
  if (nvalid && lg == 0) {
    h2[n * 2] = p0; h2[n * 2 + 1] = p1;
    as2[n] = p0 * att_s2[0] + p1 * att_s2[1];
    ad2[n] = p0 * att_d2[0] + p1 * att_d2[1];
  }
}

// ---------- layer-2 aggregation + graph mean-pool (8-lane group per node) ----------
__global__ __launch_bounds__(256) void node2_kernel(
    const int* __restrict__ ssrc, const int* __restrict__ offs, const int* __restrict__ ends,
    const float* __restrict__ h2, const float* __restrict__ as2, const float* __restrict__ ad2,
    const float* __restrict__ b2, const void* __restrict__ batch, const int* __restrict__ flags,
    float* __restrict__ pool, int nn) {
  __shared__ float psum[128];
  __shared__ float pcnt[64];
  int t = threadIdx.x;
  if (t < 128) psum[t] = 0.f;
  if (t < 64) pcnt[t] = 0.f;
  __syncthreads();
  int grp = t >> 3, lane8 = t & 7;    // 32 groups of 8 lanes
  int b64 = flags[1];
  int n = blockIdx.x * 32 + grp;
  if (n < nn) {
    float adst = ad2[n];
    int beg = offs[n], end = ends[n];
    float acc0 = 0.f, acc1 = 0.f, dsum = 0.f;
    for (int idx = beg + lane8; idx < end; idx += 8) {
      int s = ssrc[idx];
      float e = as2[s] + adst;
      e = (e < 0.f) ? 0.2f * e : e;
      float ee = __expf(e);
      float2 hv = *(const float2*)(h2 + (size_t)s * 2);
      acc0 = fmaf(ee, hv.x, acc0);
      acc1 = fmaf(ee, hv.y, acc1);
      dsum += ee;
    }
    #pragma unroll
    for (int m = 1; m < 8; m <<= 1) {
      acc0 += __shfl_xor(acc0, m);
      acc1 += __shfl_xor(acc1, m);
      dsum += __shfl_xor(dsum, m);
    }
    if (lane8 == 0) {
      float o0 = acc0 / dsum + b2[0];
      float o1 = acc1 / dsum + b2[1];
      int g = load_idx(batch, n, b64);
      atomicAdd(&psum[g * 2], o0);
      atomicAdd(&psum[g * 2 + 1], o1);
      atomicAdd(&pcnt[g], 1.f);
    }
  }
  __syncthreads();
  if (t < 64 && pcnt[t] > 0.f) {
    atomicAdd(&pool[t * 2], psum[t * 2]);
    atomicAdd(&pool[t * 2 + 1], psum[t * 2 + 1]);
    atomicAdd(&pool[128 + t], pcnt[t]);
  }
}

// ---------- mean + log_softmax ----------
__global__ void finalize_kernel(const float* __restrict__ pool, float* __restrict__ out) {
  int g = threadIdx.x;
  if (g < 64) {
    float c = fmaxf(pool[128 + g], 1.f);
    float p0 = pool[g * 2] / c, p1 = pool[g * 2 + 1] / c;
    float m = fmaxf(p0, p1);
    float lse = m + logf(expf(p0 - m) + expf(p1 - m));
    out[g * 2] = p0 - lse;
    out[g * 2 + 1] = p1 - lse;
  }
}

extern "C" void kernel_launch(void* const* d_in, const int* in_sizes, int n_in,
                              void* d_out, int out_size, void* d_ws, size_t ws_size,
                              hipStream_t stream) {
  const float* x        = (const float*)d_in[0];
  const void* eidx      = d_in[1];
  const void* batch     = d_in[2];
  const float* W1       = (const float*)d_in[3];
  const float* att_src1 = (const float*)d_in[4];
  const float* att_dst1 = (const float*)d_in[5];
  const float* b1       = (const float*)d_in[6];
  const float* W2       = (const float*)d_in[7];
  const float* att_src2 = (const float*)d_in[8];
  const float* att_dst2 = (const float*)d_in[9];
  const float* b2       = (const float*)d_in[10];
  float* out = (float*)d_out;

  int N = in_sizes[0] / 128;
  int E = in_sizes[1] / 2;
  int EP = E + N;
  int NBUK = (N + 255) >> 8;         // <= MAXBUK for N <= 131072
  int NC = NBUK * NBLK;
  int NB = (NC + 255) / 256;
  int chunk = (EP + NBLK - 1) / NBLK;

  char* ws = (char*)d_ws;
  size_t o = 0;
  auto alloc = [&](size_t bytes) -> void* {
    void* p = ws + o;
    o += (bytes + 255) & ~(size_t)255;
    return p;
  };
  u16*   h      = (u16*)alloc((size_t)N * 128 * 2);    // 25.6 MB bf16
  float* a_src1 = (float*)alloc((size_t)N * 8 * 4);
  float* a_dst1 = (float*)alloc((size_t)N * 8 * 4);
  int*   offs   = (int*)alloc((size_t)N * 4);
  int*   ends   = (int*)alloc((size_t)N * 4);
  int*   hist_g = (int*)alloc((size_t)NC * 4);         // 400 KB
  int*   base_g = (int*)alloc((size_t)NC * 4);
  int*   bsums  = (int*)alloc((size_t)(NB + 1) * 4);
  u32*   pairs  = (u32*)alloc((size_t)EP * 4);         // 6.8 MB packed
  int*   ssrc   = (int*)alloc((size_t)EP * 4);
  float* h2     = (float*)alloc((size_t)N * 2 * 4);
  float* as2    = (float*)alloc((size_t)N * 4);
  float* ad2    = (float*)alloc((size_t)N * 4);
  float* pool   = (float*)alloc(192 * 4);
  int*   flags  = (int*)alloc(2 * 4);

  detect_kernel<<<1, 64, 0, stream>>>(eidx, 2 * E, batch, N, flags);
  zero_kernel<<<1, 256, 0, stream>>>(pool);
  gemm1_kernel<<<(N + 63) / 64, 256, 0, stream>>>(x, W1, att_src1, att_dst1,
                                                  h, a_src1, a_dst1, N);
  ehist_kernel<<<NBLK, 512, 0, stream>>>(eidx, E, EP, chunk, flags, hist_g, NBUK);
  scan_blk<<<NB, 256, 0, stream>>>(hist_g, base_g, bsums, NC);
  scan_top<<<1, 1024, 0, stream>>>(bsums, NB);
  scan_add<<<NB, 256, 0, stream>>>(base_g, bsums, NC);
  escatter_kernel<<<NBLK, 512, 0, stream>>>(eidx, E, EP, chunk, flags, base_g, pairs, NBUK);
  bfinal_kernel<<<NBUK, 256, 0, stream>>>(pairs, base_g, offs, ends, ssrc, N, EP, NBUK);
  node1_kernel<<<(N + 15) / 16, 256, 0, stream>>>(ssrc, offs, ends, h, a_src1, a_dst1,
                                                  b1, W2, att_src2, att_dst2,
                                                  h2, as2, ad2, N);
  node2_kernel<<<(N + 31) / 32, 256, 0, stream>>>(ssrc, offs, ends, h2, as2, ad2,
                                                  b2, batch, flags, pool, N);
  finalize_kernel<<<1, 64, 0, stream>>>(pool, out);
}

// Round 8
// 212.493 us; speedup vs baseline: 2.7297x; 1.0071x over previous
//
#include <hip/hip_runtime.h>
#include <math.h>

typedef long long ll;
typedef unsigned int u32;
typedef unsigned short u16;
typedef __attribute__((ext_vector_type(8))) short short8;
typedef __attribute__((ext_vector_type(4))) float f32x4;

#define NBLK 256          // partition blocks
#define MAXBUK 512        // supports N <= 131072
#define CHUNK_MAX 8192    // LDS edge buffer; supports EP <= NBLK*CHUNK_MAX

__device__ __forceinline__ int load_idx(const void* p, int i, int is64) {
  return is64 ? (int)((const ll*)p)[i] : ((const int*)p)[i];
}

__device__ __forceinline__ u16 f2bf(float f) {
  u32 u = __float_as_uint(f);
  u += 0x7FFFu + ((u >> 16) & 1u);
  return (u16)(u >> 16);
}

// ---------- detect whether integer inputs are int64 or int32 ----------
__global__ void detect_kernel(const void* __restrict__ eidx, int ne,
                              const void* __restrict__ batch, int nb,
                              int* __restrict__ flags) {
  if (threadIdx.x == 0 && blockIdx.x == 0) {
    int e64 = 1;
    for (int k = 1; k <= 16; ++k) {
      int i = (int)((ll)k * (ne / 2 - 1) / 16);
      ll v = ((const ll*)eidx)[i];
      if (v < 0 || v >= (1LL << 31)) { e64 = 0; break; }
    }
    int b64 = 1;
    for (int k = 1; k <= 16; ++k) {
      int i = (int)((ll)k * (nb / 2 - 1) / 16);
      ll v = ((const ll*)batch)[i];
      if (v < 0 || v >= (1LL << 31)) { b64 = 0; break; }
    }
    flags[0] = e64; flags[1] = b64;
  }
}

// ---------- zero pool only ----------
__global__ void zero_kernel(float* __restrict__ pool) {
  int i = threadIdx.x;
  if (i < 192) pool[i] = 0.f;
}

// ---------- K1: h = x @ W1 via MFMA bf16 (f32 acc; fused a_src1/a_dst1) ----------
__global__ __launch_bounds__(256) void gemm1_kernel(
    const float* __restrict__ x, const float* __restrict__ W1,
    const float* __restrict__ att_src, const float* __restrict__ att_dst,
    u16* __restrict__ h, float* __restrict__ a_src, float* __restrict__ a_dst,
    int nn) {
  __shared__ __align__(16) char smem[64 * 136 * 2 + 128 * 136 * 2];  // 52224 B
  u16* xs = (u16*)smem;                       // [64][136]
  u16* Wt = (u16*)(smem + 64 * 136 * 2);      // [128][136]  Wt[j][k]
  float* hs = (float*)smem;                   // [64][132]   (overlay)
  int t = threadIdx.x;
  int n0 = blockIdx.x * 64;

  #pragma unroll 4
  for (int p = 0; p < 64; ++p) {
    int i = t + p * 256;          // 16384 elements
    int k = i >> 7, j = i & 127;
    u16 w = f2bf(W1[i]);
    Wt[j * 136 + k] = w;
  }
  #pragma unroll
  for (int p = 0; p < 4; ++p) {
    int row = p * 16 + (t >> 4);
    int c = t & 15;
    int gn = n0 + row;
    uint4 pk = make_uint4(0u, 0u, 0u, 0u);
    if (gn < nn) {
      const float4* xp = (const float4*)(x + (size_t)gn * 128 + c * 8);
      float4 f0 = xp[0], f1 = xp[1];
      pk.x = (u32)f2bf(f0.x) | ((u32)f2bf(f0.y) << 16);
      pk.y = (u32)f2bf(f0.z) | ((u32)f2bf(f0.w) << 16);
      pk.z = (u32)f2bf(f1.x) | ((u32)f2bf(f1.y) << 16);
      pk.w = (u32)f2bf(f1.z) | ((u32)f2bf(f1.w) << 16);
    }
    *(uint4*)&xs[row * 136 + c * 8] = pk;
  }
  __syncthreads();

  int lane = t & 63, wid = t >> 6;
  int lrow = lane & 15, lq = lane >> 4;
  short8 a[4];
  #pragma unroll
  for (int ks = 0; ks < 4; ++ks) {
    int row = wid * 16 + lrow;
    a[ks] = *(const short8*)&xs[row * 136 + ks * 32 + lq * 8];
  }
  f32x4 c[8];
  #pragma unroll
  for (int jt = 0; jt < 8; ++jt) c[jt] = (f32x4)(0.f);
  #pragma unroll
  for (int jt = 0; jt < 8; ++jt) {
    int j = jt * 16 + lrow;
    #pragma unroll
    for (int ks = 0; ks < 4; ++ks) {
      short8 b = *(const short8*)&Wt[j * 136 + ks * 32 + lq * 8];
      c[jt] = __builtin_amdgcn_mfma_f32_16x16x32_bf16(a[ks], b, c[jt], 0, 0, 0);
    }
  }
  __syncthreads();

  #pragma unroll
  for (int jt = 0; jt < 8; ++jt) {
    #pragma unroll
    for (int r = 0; r < 4; ++r) {
      hs[(wid * 16 + lq * 4 + r) * 132 + jt * 16 + lrow] = c[jt][r];
    }
  }
  __syncthreads();

  int q = t & 31, p = t >> 5;
  const float4 as4 = ((const float4*)att_src)[q];
  const float4 ad4 = ((const float4*)att_dst)[q];
  int head = q >> 2;
  #pragma unroll
  for (int rr = 0; rr < 8; ++rr) {
    int row = rr * 8 + p;
    int n = n0 + row;
    float4 v = *(const float4*)&hs[row * 132 + q * 4];
    float s = v.x * as4.x + v.y * as4.y + v.z * as4.z + v.w * as4.w;
    float d = v.x * ad4.x + v.y * ad4.y + v.z * ad4.z + v.w * ad4.w;
    s += __shfl_xor(s, 1); s += __shfl_xor(s, 2);
    d += __shfl_xor(d, 1); d += __shfl_xor(d, 2);
    if (n < nn) {
      uint2 pk;
      pk.x = (u32)f2bf(v.x) | ((u32)f2bf(v.y) << 16);
      pk.y = (u32)f2bf(v.z) | ((u32)f2bf(v.w) << 16);
      ((uint2*)(h + (size_t)n * 128))[q] = pk;
      if ((q & 3) == 0) { a_src[n * 8 + head] = s; a_dst[n * 8 + head] = d; }
    }
  }
}

// ---------- per-block LDS histogram of dst buckets ----------
__global__ __launch_bounds__(512) void ehist_kernel(
    const void* __restrict__ eidx, int E, int EP, int chunk,
    const int* __restrict__ flags, int* __restrict__ hist_g, int nbuk) {
  __shared__ int cnt[MAXBUK];
  int t = threadIdx.x, blk = blockIdx.x;
  if (t < MAXBUK) cnt[t] = 0;
  __syncthreads();
  int lo = blk * chunk, hi = min(lo + chunk, EP);
  int is64 = flags[0];
  for (int i = lo + t; i < hi; i += 512) {
    int d = (i < E) ? load_idx(eidx, E + i, is64) : (i - E);
    atomicAdd(&cnt[d >> 8], 1);
  }
  __syncthreads();
  if (t < nbuk) hist_g[t * NBLK + blk] = cnt[t];
}

// ---------- two-level exclusive scan over nbuk*NBLK counters ----------
__global__ __launch_bounds__(256) void scan_blk(const int* __restrict__ in,
                                                int* __restrict__ out,
                                                int* __restrict__ bsums, int n) {
  int t = threadIdx.x;
  int i = blockIdx.x * 256 + t;
  int v = (i < n) ? in[i] : 0;
  int lane = t & 63, w = t >> 6;
  int s = v;
  #pragma unroll
  for (int off = 1; off < 64; off <<= 1) {
    int u = __shfl_up(s, off);
    if (lane >= off) s += u;
  }
  __shared__ int wsum[4];
  if (lane == 63) wsum[w] = s;
  __syncthreads();
  int add = 0;
  for (int k = 0; k < w; ++k) add += wsum[k];
  int incl = s + add;
  if (i < n) out[i] = incl - v;
  if (t == 255) bsums[blockIdx.x] = incl;
}

__global__ __launch_bounds__(1024) void scan_top(int* __restrict__ bsums, int nb) {
  int t = threadIdx.x;
  int v = (t < nb) ? bsums[t] : 0;
  int lane = t & 63, w = t >> 6;
  int s = v;
  #pragma unroll
  for (int off = 1; off < 64; off <<= 1) {
    int u = __shfl_up(s, off);
    if (lane >= off) s += u;
  }
  __shared__ int ws[16];
  if (lane == 63) ws[w] = s;
  __syncthreads();
  int add = 0;
  for (int k = 0; k < w; ++k) add += ws[k];
  if (t < nb) bsums[t] = s + add - v;
}

__global__ void scan_add(int* __restrict__ out, const int* __restrict__ bsums, int n) {
  int i = blockIdx.x * 256 + threadIdx.x;
  if (i < n) out[i] += bsums[blockIdx.x];
}

// ---------- scatter via LDS staging: dense per-run global writes ----------
__global__ __launch_bounds__(512) void escatter_kernel(
    const void* __restrict__ eidx, int E, int EP, int chunk,
    const int* __restrict__ flags, const int* __restrict__ hist_g,
    const int* __restrict__ base_g, u32* __restrict__ pairs, int nbuk) {
  __shared__ int cnt[MAXBUK];
  __shared__ int lbase[MAXBUK];
  __shared__ int lcur[MAXBUK];
  __shared__ u32 buf[CHUNK_MAX];
  __shared__ int wsum[8];
  int t = threadIdx.x, blk = blockIdx.x;
  int v = 0;
  if (t < nbuk) { v = hist_g[t * NBLK + blk]; cnt[t] = v; }
  // block-local exclusive scan of cnt (512 slots, zeros past nbuk)
  int lane = t & 63, w = t >> 6;
  int s = v;
  #pragma unroll
  for (int off = 1; off < 64; off <<= 1) {
    int u = __shfl_up(s, off);
    if (lane >= off) s += u;
  }
  if (lane == 63) wsum[w] = s;
  __syncthreads();
  int add = 0;
  for (int k = 0; k < w; ++k) add += wsum[k];
  if (t < nbuk) { lbase[t] = s + add - v; lcur[t] = s + add - v; }
  __syncthreads();
  int lo = blk * chunk, hi = min(lo + chunk, EP);
  int is64 = flags[0];
  for (int i = lo + t; i < hi; i += 512) {
    int sv, d;
    if (i < E) { sv = load_idx(eidx, i, is64); d = load_idx(eidx, E + i, is64); }
    else { sv = d = i - E; }
    int pos = atomicAdd(&lcur[d >> 8], 1);
    buf[pos] = ((u32)(d & 255) << 24) | (u32)sv;
  }
  __syncthreads();
  // dense write-out: wave w copies buckets w, w+8, ...
  for (int b = w; b < nbuk; b += 8) {
    int n_b = cnt[b];
    int lb = lbase[b];
    int gb = base_g[b * NBLK + blk];
    for (int k = lane; k < n_b; k += 64) {
      pairs[gb + k] = buf[lb + k];
    }
  }
}

// ---------- per-bucket local sort: LDS hist+scan, write offs/ends/ssrc ----------
__global__ __launch_bounds__(256) void bfinal_kernel(
    const u32* __restrict__ pairs, const int* __restrict__ base_g,
    int* __restrict__ offs, int* __restrict__ ends, int* __restrict__ ssrc,
    int N, int EP, int nbuk) {
  int b = blockIdx.x, t = threadIdx.x;
  int nb0 = b << 8;
  __shared__ int cnt[256];
  __shared__ int cur[256];
  __shared__ int wsum[4];
  cnt[t] = 0;
  __syncthreads();
  int seg_start = base_g[b * NBLK];
  int seg_end = (b + 1 < nbuk) ? base_g[(b + 1) * NBLK] : EP;
  for (int i = seg_start + t; i < seg_end; i += 256) {
    atomicAdd(&cnt[pairs[i] >> 24], 1);
  }
  __syncthreads();
  int v = cnt[t];
  int lane = t & 63, w = t >> 6;
  int s = v;
  #pragma unroll
  for (int off = 1; off < 64; off <<= 1) {
    int u = __shfl_up(s, off);
    if (lane >= off) s += u;
  }
  if (lane == 63) wsum[w] = s;
  __syncthreads();
  int add = 0;
  for (int k = 0; k < w; ++k) add += wsum[k];
  int excl = s + add - v;
  cur[t] = excl;
  int node = nb0 + t;
  if (node < N) { offs[node] = seg_start + excl; ends[node] = seg_start + excl + v; }
  __syncthreads();
  for (int i = seg_start + t; i < seg_end; i += 256) {
    u32 p = pairs[i];
    int pos = atomicAdd(&cur[p >> 24], 1);
    ssrc[seg_start + pos] = (int)(p & 0xFFFFFFu);
  }
}

// ---------- layer-1 aggregation + ELU + layer-2 projection ----------
// (round-6 body; epilogue writes packed rec = {p0, p1, as2, ad2})
__global__ __launch_bounds__(256) void node1_kernel(
    const int* __restrict__ ssrc, const int* __restrict__ offs, const int* __restrict__ ends,
    const u16* __restrict__ h, const float* __restrict__ a_src, const float* __restrict__ a_dst,
    const float* __restrict__ b1, const float* __restrict__ W2,
    const float* __restrict__ att_s2, const float* __restrict__ att_d2,
    float4* __restrict__ rec, int nn) {
  int t = threadIdx.x;
  int wid = t >> 6, lane = t & 63;
  int grp = lane >> 4, lg = lane & 15;      // 4 node-groups of 16 lanes
  int n = blockIdx.x * 16 + wid * 4 + grp;
  bool nvalid = (n < nn);
  int nc = nvalid ? n : (nn - 1);
  int hh = lg >> 1;                          // head for this lane's 8 dims
  float adst = a_dst[nc * 8 + hh];
  int beg = offs[nc], end = ends[nc];
  int deg = nvalid ? (end - beg) : 0;
  int maxd = deg;
  maxd = max(maxd, __shfl_xor(maxd, 16));
  maxd = max(maxd, __shfl_xor(maxd, 32));    // wave-wide max degree
  float acc[8];
  #pragma unroll
  for (int k = 0; k < 8; ++k) acc[k] = 0.f;
  float dsum = 0.f;
  const u32* h32 = (const u32*)h;
  for (int it = 0; it < maxd; it += 4) {
    int s4[4]; float ea4[4]; uint4 v4[4];
    #pragma unroll
    for (int u = 0; u < 4; ++u) {
      int id = beg + it + u;
      s4[u] = ssrc[id < end ? id : end - 1];
    }
    #pragma unroll
    for (int u = 0; u < 4; ++u) {
      v4[u]  = *(const uint4*)(h32 + s4[u] * 64 + lg * 4);
      ea4[u] = a_src[s4[u] * 8 + hh];
    }
    #pragma unroll
    for (int u = 0; u < 4; ++u) {
      float e = ea4[u] + adst;
      e = fmaxf(e, 0.2f * e);                 // leaky_relu
      float ee = (it + u < deg) ? __expf(e) : 0.f;
      dsum += ee;
      acc[0] = fmaf(ee, __uint_as_float(v4[u].x << 16),          acc[0]);
      acc[1] = fmaf(ee, __uint_as_float(v4[u].x & 0xFFFF0000u),  acc[1]);
      acc[2] = fmaf(ee, __uint_as_float(v4[u].y << 16),          acc[2]);
      acc[3] = fmaf(ee, __uint_as_float(v4[u].y & 0xFFFF0000u),  acc[3]);
      acc[4] = fmaf(ee, __uint_as_float(v4[u].z << 16),          acc[4]);
      acc[5] = fmaf(ee, __uint_as_float(v4[u].z & 0xFFFF0000u),  acc[5]);
      acc[6] = fmaf(ee, __uint_as_float(v4[u].w << 16),          acc[6]);
      acc[7] = fmaf(ee, __uint_as_float(v4[u].w & 0xFFFF0000u),  acc[7]);
    }
  }
  float inv = 1.f / dsum;                     // lane-local denominator
  float p0 = 0.f, p1 = 0.f;
  #pragma unroll
  for (int k = 0; k < 8; ++k) {
    int j = lg * 8 + k;
    float o = acc[k] * inv + b1[j];
    o = (o > 0.f) ? o : expm1f(o);            // ELU
    p0 = fmaf(o, W2[j * 2],     p0);
    p1 = fmaf(o, W2[j * 2 + 1], p1);
  }
  #pragma unroll
  for (int m = 1; m < 16; m <<= 1) { p0 += __shfl_xor(p0, m); p1 += __shfl_xor(p1, m); }
  if (nvalid && lg == 0) {
    rec[n] = make_float4(p0, p1,
                         p0 * att_s2[0] + p1 * att_s2[1],
                         p0 * att_d2[0] + p1 * att_d2[1]);
  }
}

// ---------- layer-2 aggregation + graph mean-pool (8-lane group per node) ----------
__global__ __launch_bounds__(256) void node2_kernel(
    const int* __restrict__ ssrc, const int* __restrict__ offs, const int* __restrict__ ends,
    const float4* __restrict__ rec, const float* __restrict__ b2,
    const void* __restrict__ batch, const int* __restrict__ flags,
    float* __restrict__ pool, int nn) {
  __shared__ float psum[128];
  __shared__ float pcnt[64];
  int t = threadIdx.x;
  if (t < 128) psum[t] = 0.f;
  if (t < 64) pcnt[t] = 0.f;
  __syncthreads();
  int grp = t >> 3, lane8 = t & 7;    // 32 groups of 8 lanes
  int b64 = flags[1];
  int n = blockIdx.x * 32 + grp;
  if (n < nn) {
    float adst = rec[n].w;
    int beg = offs[n], end = ends[n];
    float acc0 = 0.f, acc1 = 0.f, dsum = 0.f;
    for (int idx = beg + lane8; idx < end; idx += 8) {
      int s = ssrc[idx];
      float4 r = rec[s];                // one 16B gather: {p0,p1,as2,ad2}
      float e = r.z + adst;
      e = (e < 0.f) ? 0.2f * e : e;
      float ee = __expf(e);
      acc0 = fmaf(ee, r.x, acc0);
      acc1 = fmaf(ee, r.y, acc1);
      dsum += ee;
    }
    #pragma unroll
    for (int m = 1; m < 8; m <<= 1) {
      acc0 += __shfl_xor(acc0, m);
      acc1 += __shfl_xor(acc1, m);
      dsum += __shfl_xor(dsum, m);
    }
    if (lane8 == 0) {
      float o0 = acc0 / dsum + b2[0];
      float o1 = acc1 / dsum + b2[1];
      int g = load_idx(batch, n, b64);
      atomicAdd(&psum[g * 2], o0);
      atomicAdd(&psum[g * 2 + 1], o1);
      atomicAdd(&pcnt[g], 1.f);
    }
  }
  __syncthreads();
  if (t < 64 && pcnt[t] > 0.f) {
    atomicAdd(&pool[t * 2], psum[t * 2]);
    atomicAdd(&pool[t * 2 + 1], psum[t * 2 + 1]);
    atomicAdd(&pool[128 + t], pcnt[t]);
  }
}

// ---------- mean + log_softmax ----------
__global__ void finalize_kernel(const float* __restrict__ pool, float* __restrict__ out) {
  int g = threadIdx.x;
  if (g < 64) {
    float c = fmaxf(pool[128 + g], 1.f);
    float p0 = pool[g * 2] / c, p1 = pool[g * 2 + 1] / c;
    float m = fmaxf(p0, p1);
    float lse = m + logf(expf(p0 - m) + expf(p1 - m));
    out[g * 2] = p0 - lse;
    out[g * 2 + 1] = p1 - lse;
  }
}

extern "C" void kernel_launch(void* const* d_in, const int* in_sizes, int n_in,
                              void* d_out, int out_size, void* d_ws, size_t ws_size,
                              hipStream_t stream) {
  const float* x        = (const float*)d_in[0];
  const void* eidx      = d_in[1];
  const void* batch     = d_in[2];
  const float* W1       = (const float*)d_in[3];
  const float* att_src1 = (const float*)d_in[4];
  const float* att_dst1 = (const float*)d_in[5];
  const float* b1       = (const float*)d_in[6];
  const float* W2       = (const float*)d_in[7];
  const float* att_src2 = (const float*)d_in[8];
  const float* att_dst2 = (const float*)d_in[9];
  const float* b2       = (const float*)d_in[10];
  float* out = (float*)d_out;

  int N = in_sizes[0] / 128;
  int E = in_sizes[1] / 2;
  int EP = E + N;
  int NBUK = (N + 255) >> 8;         // <= MAXBUK for N <= 131072
  int NC = NBUK * NBLK;
  int NB = (NC + 255) / 256;
  int chunk = (((EP + NBLK - 1) / NBLK) + 1) & ~1;   // even, <= CHUNK_MAX

  char* ws = (char*)d_ws;
  size_t o = 0;
  auto alloc = [&](size_t bytes) -> void* {
    void* p = ws + o;
    o += (bytes + 255) & ~(size_t)255;
    return p;
  };
  u16*   h      = (u16*)alloc((size_t)N * 128 * 2);    // 25.6 MB bf16
  float* a_src1 = (float*)alloc((size_t)N * 8 * 4);
  float* a_dst1 = (float*)alloc((size_t)N * 8 * 4);
  int*   offs   = (int*)alloc((size_t)N * 4);
  int*   ends   = (int*)alloc((size_t)N * 4);
  int*   hist_g = (int*)alloc((size_t)NC * 4);         // 400 KB
  int*   base_g = (int*)alloc((size_t)NC * 4);
  int*   bsums  = (int*)alloc((size_t)(NB + 1) * 4);
  u32*   pairs  = (u32*)alloc((size_t)EP * 4);         // 6.8 MB packed
  int*   ssrc   = (int*)alloc((size_t)EP * 4);
  float4* rec   = (float4*)alloc((size_t)N * 16);      // {p0,p1,as2,ad2}
  float* pool   = (float*)alloc(192 * 4);
  int*   flags  = (int*)alloc(2 * 4);

  detect_kernel<<<1, 64, 0, stream>>>(eidx, 2 * E, batch, N, flags);
  zero_kernel<<<1, 256, 0, stream>>>(pool);
  gemm1_kernel<<<(N + 63) / 64, 256, 0, stream>>>(x, W1, att_src1, att_dst1,
                                                  h, a_src1, a_dst1, N);
  ehist_kernel<<<NBLK, 512, 0, stream>>>(eidx, E, EP, chunk, flags, hist_g, NBUK);
  scan_blk<<<NB, 256, 0, stream>>>(hist_g, base_g, bsums, NC);
  scan_top<<<1, 1024, 0, stream>>>(bsums, NB);
  scan_add<<<NB, 256, 0, stream>>>(base_g, bsums, NC);
  escatter_kernel<<<NBLK, 512, 0, stream>>>(eidx, E, EP, chunk, flags, hist_g,
                                            base_g, pairs, NBUK);
  bfinal_kernel<<<NBUK, 256, 0, stream>>>(pairs, base_g, offs, ends, ssrc, N, EP, NBUK);
  node1_kernel<<<(N + 15) / 16, 256, 0, stream>>>(ssrc, offs, ends, h, a_src1, a_dst1,
                                                  b1, W2, att_src2, att_dst2,
                                                  rec, N);
  node2_kernel<<<(N + 31) / 32, 256, 0, stream>>>(ssrc, offs, ends, rec,
                                                  b2, batch, flags, pool, N);
  finalize_kernel<<<1, 64, 0, stream>>>(pool, out);
}

// Round 9
// 204.842 us; speedup vs baseline: 2.8317x; 1.0373x over previous
//
#include <hip/hip_runtime.h>
#include <math.h>

typedef long long ll;
typedef unsigned int u32;
typedef unsigned short u16;
typedef __attribute__((ext_vector_type(8))) short short8;
typedef __attribute__((ext_vector_type(4))) float f32x4;

#define NBLK 256          // partition blocks
#define MAXBUK 512        // supports N <= 131072
#define CHUNK_MAX 8192    // LDS edge buffer; supports EP <= NBLK*CHUNK_MAX

__device__ __forceinline__ int load_idx(const void* p, int i, int is64) {
  return is64 ? (int)((const ll*)p)[i] : ((const int*)p)[i];
}

__device__ __forceinline__ u16 f2bf(float f) {
  u32 u = __float_as_uint(f);
  u += 0x7FFFu + ((u >> 16) & 1u);
  return (u16)(u >> 16);
}

// ---------- prep: W1->bf16^T precompute + detect(parallel) + zero pool ----------
__global__ __launch_bounds__(256) void prep_kernel(
    const void* __restrict__ eidx, int ne2, const void* __restrict__ batch, int nb,
    const float* __restrict__ W1, u16* __restrict__ Wtb,
    float* __restrict__ pool, int* __restrict__ flags) {
  int blk = blockIdx.x, t = threadIdx.x;
  if (blk < 64) {
    int g = blk * 256 + t;          // 16384 elements of W1[k][j]
    int k = g >> 7, j = g & 127;
    Wtb[j * 128 + k] = f2bf(W1[g]);
  } else {
    if (t < 192) pool[t] = 0.f;
    ll v = 0;
    if (t < 16) {
      int i = (int)((ll)(t + 1) * (ne2 / 2 - 1) / 16);
      v = ((const ll*)eidx)[i];
    } else if (t < 32) {
      int i = (int)((ll)(t - 15) * (nb / 2 - 1) / 16);
      v = ((const ll*)batch)[i];
    }
    bool bad = (v < 0 || v >= (1LL << 31));
    unsigned long long mask = __ballot(bad);
    if (t == 0) {
      flags[0] = (mask & 0xFFFFull) ? 0 : 1;          // edge_index is64
      flags[1] = (mask & 0xFFFF0000ull) ? 0 : 1;      // batch is64
    }
  }
}

// ---------- K1: h = x @ W1 via MFMA bf16 (f32 acc; fused a_src1/a_dst1) ----------
__global__ __launch_bounds__(256) void gemm1_kernel(
    const float* __restrict__ x, const u16* __restrict__ Wtb,
    const float* __restrict__ att_src, const float* __restrict__ att_dst,
    u16* __restrict__ h, float* __restrict__ a_src, float* __restrict__ a_dst,
    int nn) {
  __shared__ __align__(16) char smem[64 * 136 * 2 + 128 * 136 * 2];  // 52224 B
  u16* xs = (u16*)smem;                       // [64][136]
  u16* Wt = (u16*)(smem + 64 * 136 * 2);      // [128][136]  Wt[j][k]
  float* hs = (float*)smem;                   // [64][132]   (overlay)
  int t = threadIdx.x;
  int n0 = blockIdx.x * 64;

  // stage Wt from precomputed bf16 (8 x uint4 per thread)
  const uint4* W4 = (const uint4*)Wtb;        // 2048 uint4
  #pragma unroll
  for (int p = 0; p < 8; ++p) {
    int i = t + p * 256;
    int j = i >> 4, kc = (i & 15) * 8;
    *(uint4*)&Wt[j * 136 + kc] = W4[i];
  }
  #pragma unroll
  for (int p = 0; p < 4; ++p) {
    int row = p * 16 + (t >> 4);
    int c = t & 15;
    int gn = n0 + row;
    uint4 pk = make_uint4(0u, 0u, 0u, 0u);
    if (gn < nn) {
      const float4* xp = (const float4*)(x + (size_t)gn * 128 + c * 8);
      float4 f0 = xp[0], f1 = xp[1];
      pk.x = (u32)f2bf(f0.x) | ((u32)f2bf(f0.y) << 16);
      pk.y = (u32)f2bf(f0.z) | ((u32)f2bf(f0.w) << 16);
      pk.z = (u32)f2bf(f1.x) | ((u32)f2bf(f1.y) << 16);
      pk.w = (u32)f2bf(f1.z) | ((u32)f2bf(f1.w) << 16);
    }
    *(uint4*)&xs[row * 136 + c * 8] = pk;
  }
  __syncthreads();

  int lane = t & 63, wid = t >> 6;
  int lrow = lane & 15, lq = lane >> 4;
  short8 a[4];
  #pragma unroll
  for (int ks = 0; ks < 4; ++ks) {
    int row = wid * 16 + lrow;
    a[ks] = *(const short8*)&xs[row * 136 + ks * 32 + lq * 8];
  }
  f32x4 c[8];
  #pragma unroll
  for (int jt = 0; jt < 8; ++jt) c[jt] = (f32x4)(0.f);
  #pragma unroll
  for (int jt = 0; jt < 8; ++jt) {
    int j = jt * 16 + lrow;
    #pragma unroll
    for (int ks = 0; ks < 4; ++ks) {
      short8 b = *(const short8*)&Wt[j * 136 + ks * 32 + lq * 8];
      c[jt] = __builtin_amdgcn_mfma_f32_16x16x32_bf16(a[ks], b, c[jt], 0, 0, 0);
    }
  }
  __syncthreads();

  #pragma unroll
  for (int jt = 0; jt < 8; ++jt) {
    #pragma unroll
    for (int r = 0; r < 4; ++r) {
      hs[(wid * 16 + lq * 4 + r) * 132 + jt * 16 + lrow] = c[jt][r];
    }
  }
  __syncthreads();

  int q = t & 31, p = t >> 5;
  const float4 as4 = ((const float4*)att_src)[q];
  const float4 ad4 = ((const float4*)att_dst)[q];
  int head = q >> 2;
  #pragma unroll
  for (int rr = 0; rr < 8; ++rr) {
    int row = rr * 8 + p;
    int n = n0 + row;
    float4 v = *(const float4*)&hs[row * 132 + q * 4];
    float s = v.x * as4.x + v.y * as4.y + v.z * as4.z + v.w * as4.w;
    float d = v.x * ad4.x + v.y * ad4.y + v.z * ad4.z + v.w * ad4.w;
    s += __shfl_xor(s, 1); s += __shfl_xor(s, 2);
    d += __shfl_xor(d, 1); d += __shfl_xor(d, 2);
    if (n < nn) {
      uint2 pk;
      pk.x = (u32)f2bf(v.x) | ((u32)f2bf(v.y) << 16);
      pk.y = (u32)f2bf(v.z) | ((u32)f2bf(v.w) << 16);
      ((uint2*)(h + (size_t)n * 128))[q] = pk;
      if ((q & 3) == 0) { a_src[n * 8 + head] = s; a_dst[n * 8 + head] = d; }
    }
  }
}

// ---------- per-block LDS histogram of dst buckets ----------
__global__ __launch_bounds__(512) void ehist_kernel(
    const void* __restrict__ eidx, int E, int EP, int chunk,
    const int* __restrict__ flags, int* __restrict__ hist_g, int nbuk) {
  __shared__ int cnt[MAXBUK];
  int t = threadIdx.x, blk = blockIdx.x;
  if (t < MAXBUK) cnt[t] = 0;
  __syncthreads();
  int lo = blk * chunk, hi = min(lo + chunk, EP);
  int is64 = flags[0];
  for (int i = lo + t; i < hi; i += 512) {
    int d = (i < E) ? load_idx(eidx, E + i, is64) : (i - E);
    atomicAdd(&cnt[d >> 8], 1);
  }
  __syncthreads();
  if (t < nbuk) hist_g[t * NBLK + blk] = cnt[t];
}

// ---------- two-level exclusive scan (partial per-block; bsums holds block offsets) ----------
__global__ __launch_bounds__(256) void scan_blk(const int* __restrict__ in,
                                                int* __restrict__ out,
                                                int* __restrict__ bsums, int n) {
  int t = threadIdx.x;
  int i = blockIdx.x * 256 + t;
  int v = (i < n) ? in[i] : 0;
  int lane = t & 63, w = t >> 6;
  int s = v;
  #pragma unroll
  for (int off = 1; off < 64; off <<= 1) {
    int u = __shfl_up(s, off);
    if (lane >= off) s += u;
  }
  __shared__ int wsum[4];
  if (lane == 63) wsum[w] = s;
  __syncthreads();
  int add = 0;
  for (int k = 0; k < w; ++k) add += wsum[k];
  int incl = s + add;
  if (i < n) out[i] = incl - v;
  if (t == 255) bsums[blockIdx.x] = incl;
}

__global__ __launch_bounds__(1024) void scan_top(int* __restrict__ bsums, int nb) {
  int t = threadIdx.x;
  int v = (t < nb) ? bsums[t] : 0;
  int lane = t & 63, w = t >> 6;
  int s = v;
  #pragma unroll
  for (int off = 1; off < 64; off <<= 1) {
    int u = __shfl_up(s, off);
    if (lane >= off) s += u;
  }
  __shared__ int ws[16];
  if (lane == 63) ws[w] = s;
  __syncthreads();
  int add = 0;
  for (int k = 0; k < w; ++k) add += ws[k];
  if (t < nb) bsums[t] = s + add - v;
}

// ---------- scatter via LDS staging: dense per-run global writes ----------
// global base = pbase[idx] + bsums[idx>>8]; idx = buk*NBLK+blk  ->  idx>>8 == buk
__global__ __launch_bounds__(512) void escatter_kernel(
    const void* __restrict__ eidx, int E, int EP, int chunk,
    const int* __restrict__ flags, const int* __restrict__ hist_g,
    const int* __restrict__ pbase, const int* __restrict__ bsums,
    u32* __restrict__ pairs, int nbuk) {
  __shared__ int cnt[MAXBUK];
  __shared__ int lbase[MAXBUK];
  __shared__ int lcur[MAXBUK];
  __shared__ u32 buf[CHUNK_MAX];
  __shared__ int wsum[8];
  int t = threadIdx.x, blk = blockIdx.x;
  int v = 0;
  if (t < nbuk) { v = hist_g[t * NBLK + blk]; cnt[t] = v; }
  int lane = t & 63, w = t >> 6;
  int s = v;
  #pragma unroll
  for (int off = 1; off < 64; off <<= 1) {
    int u = __shfl_up(s, off);
    if (lane >= off) s += u;
  }
  if (lane == 63) wsum[w] = s;
  __syncthreads();
  int add = 0;
  for (int k = 0; k < w; ++k) add += wsum[k];
  if (t < nbuk) { lbase[t] = s + add - v; lcur[t] = s + add - v; }
  __syncthreads();
  int lo = blk * chunk, hi = min(lo + chunk, EP);
  int is64 = flags[0];
  for (int i = lo + t; i < hi; i += 512) {
    int sv, d;
    if (i < E) { sv = load_idx(eidx, i, is64); d = load_idx(eidx, E + i, is64); }
    else { sv = d = i - E; }
    int pos = atomicAdd(&lcur[d >> 8], 1);
    buf[pos] = ((u32)(d & 255) << 24) | (u32)sv;
  }
  __syncthreads();
  for (int b = w; b < nbuk; b += 8) {
    int n_b = cnt[b];
    int lb = lbase[b];
    int gb = pbase[b * NBLK + blk] + bsums[b];
    for (int k = lane; k < n_b; k += 64) {
      pairs[gb + k] = buf[lb + k];
    }
  }
}

// ---------- per-bucket local sort: LDS hist+scan, write offs/ends/ssrc ----------
__global__ __launch_bounds__(256) void bfinal_kernel(
    const u32* __restrict__ pairs, const int* __restrict__ pbase,
    const int* __restrict__ bsums,
    int* __restrict__ offs, int* __restrict__ ends, int* __restrict__ ssrc,
    int N, int EP, int nbuk) {
  int b = blockIdx.x, t = threadIdx.x;
  int nb0 = b << 8;
  __shared__ int cnt[256];
  __shared__ int cur[256];
  __shared__ int wsum[4];
  cnt[t] = 0;
  __syncthreads();
  int seg_start = pbase[b * NBLK] + bsums[b];
  int seg_end = (b + 1 < nbuk) ? (pbase[(b + 1) * NBLK] + bsums[b + 1]) : EP;
  for (int i = seg_start + t; i < seg_end; i += 256) {
    atomicAdd(&cnt[pairs[i] >> 24], 1);
  }
  __syncthreads();
  int v = cnt[t];
  int lane = t & 63, w = t >> 6;
  int s = v;
  #pragma unroll
  for (int off = 1; off < 64; off <<= 1) {
    int u = __shfl_up(s, off);
    if (lane >= off) s += u;
  }
  if (lane == 63) wsum[w] = s;
  __syncthreads();
  int add = 0;
  for (int k = 0; k < w; ++k) add += wsum[k];
  int excl = s + add - v;
  cur[t] = excl;
  int node = nb0 + t;
  if (node < N) { offs[node] = seg_start + excl; ends[node] = seg_start + excl + v; }
  __syncthreads();
  for (int i = seg_start + t; i < seg_end; i += 256) {
    u32 p = pairs[i];
    int pos = atomicAdd(&cur[p >> 24], 1);
    ssrc[seg_start + pos] = (int)(p & 0xFFFFFFu);
  }
}

// ---------- layer-1 aggregation + ELU + layer-2 projection ----------
__global__ __launch_bounds__(256) void node1_kernel(
    const int* __restrict__ ssrc, const int* __restrict__ offs, const int* __restrict__ ends,
    const u16* __restrict__ h, const float* __restrict__ a_src, const float* __restrict__ a_dst,
    const float* __restrict__ b1, const float* __restrict__ W2,
    const float* __restrict__ att_s2, const float* __restrict__ att_d2,
    float4* __restrict__ rec, int nn) {
  int t = threadIdx.x;
  int wid = t >> 6, lane = t & 63;
  int grp = lane >> 4, lg = lane & 15;      // 4 node-groups of 16 lanes
  int n = blockIdx.x * 16 + wid * 4 + grp;
  bool nvalid = (n < nn);
  int nc = nvalid ? n : (nn - 1);
  int hh = lg >> 1;                          // head for this lane's 8 dims
  float adst = a_dst[nc * 8 + hh];
  int beg = offs[nc], end = ends[nc];
  int deg = nvalid ? (end - beg) : 0;
  int maxd = deg;
  maxd = max(maxd, __shfl_xor(maxd, 16));
  maxd = max(maxd, __shfl_xor(maxd, 32));    // wave-wide max degree
  float acc[8];
  #pragma unroll
  for (int k = 0; k < 8; ++k) acc[k] = 0.f;
  float dsum = 0.f;
  const u32* h32 = (const u32*)h;
  for (int it = 0; it < maxd; it += 4) {
    int s4[4]; float ea4[4]; uint4 v4[4];
    #pragma unroll
    for (int u = 0; u < 4; ++u) {
      int id = beg + it + u;
      s4[u] = ssrc[id < end ? id : end - 1];
    }
    #pragma unroll
    for (int u = 0; u < 4; ++u) {
      v4[u]  = *(const uint4*)(h32 + s4[u] * 64 + lg * 4);
      ea4[u] = a_src[s4[u] * 8 + hh];
    }
    #pragma unroll
    for (int u = 0; u < 4; ++u) {
      float e = ea4[u] + adst;
      e = fmaxf(e, 0.2f * e);                 // leaky_relu
      float ee = (it + u < deg) ? __expf(e) : 0.f;
      dsum += ee;
      acc[0] = fmaf(ee, __uint_as_float(v4[u].x << 16),          acc[0]);
      acc[1] = fmaf(ee, __uint_as_float(v4[u].x & 0xFFFF0000u),  acc[1]);
      acc[2] = fmaf(ee, __uint_as_float(v4[u].y << 16),          acc[2]);
      acc[3] = fmaf(ee, __uint_as_float(v4[u].y & 0xFFFF0000u),  acc[3]);
      acc[4] = fmaf(ee, __uint_as_float(v4[u].z << 16),          acc[4]);
      acc[5] = fmaf(ee, __uint_as_float(v4[u].z & 0xFFFF0000u),  acc[5]);
      acc[6] = fmaf(ee, __uint_as_float(v4[u].w << 16),          acc[6]);
      acc[7] = fmaf(ee, __uint_as_float(v4[u].w & 0xFFFF0000u),  acc[7]);
    }
  }
  float inv = 1.f / dsum;                     // lane-local denominator
  float p0 = 0.f, p1 = 0.f;
  #pragma unroll
  for (int k = 0; k < 8; ++k) {
    int j = lg * 8 + k;
    float o = acc[k] * inv + b1[j];
    o = (o > 0.f) ? o : expm1f(o);            // ELU
    p0 = fmaf(o, W2[j * 2],     p0);
    p1 = fmaf(o, W2[j * 2 + 1], p1);
  }
  #pragma unroll
  for (int m = 1; m < 16; m <<= 1) { p0 += __shfl_xor(p0, m); p1 += __shfl_xor(p1, m); }
  if (nvalid && lg == 0) {
    rec[n] = make_float4(p0, p1,
                         p0 * att_s2[0] + p1 * att_s2[1],
                         p0 * att_d2[0] + p1 * att_d2[1]);
  }
}

// ---------- layer-2 aggregation + graph mean-pool (8-lane group per node) ----------
__global__ __launch_bounds__(256) void node2_kernel(
    const int* __restrict__ ssrc, const int* __restrict__ offs, const int* __restrict__ ends,
    const float4* __restrict__ rec, const float* __restrict__ b2,
    const void* __restrict__ batch, const int* __restrict__ flags,
    float* __restrict__ pool, int nn) {
  __shared__ float psum[128];
  __shared__ float pcnt[64];
  int t = threadIdx.x;
  if (t < 128) psum[t] = 0.f;
  if (t < 64) pcnt[t] = 0.f;
  __syncthreads();
  int grp = t >> 3, lane8 = t & 7;    // 32 groups of 8 lanes
  int b64 = flags[1];
  int n = blockIdx.x * 32 + grp;
  if (n < nn) {
    float adst = rec[n].w;
    int beg = offs[n], end = ends[n];
    float acc0 = 0.f, acc1 = 0.f, dsum = 0.f;
    for (int idx = beg + lane8; idx < end; idx += 8) {
      int s = ssrc[idx];
      float4 r = rec[s];                // one 16B gather: {p0,p1,as2,ad2}
      float e = r.z + adst;
      e = (e < 0.f) ? 0.2f * e : e;
      float ee = __expf(e);
      acc0 = fmaf(ee, r.x, acc0);
      acc1 = fmaf(ee, r.y, acc1);
      dsum += ee;
    }
    #pragma unroll
    for (int m = 1; m < 8; m <<= 1) {
      acc0 += __shfl_xor(acc0, m);
      acc1 += __shfl_xor(acc1, m);
      dsum += __shfl_xor(dsum, m);
    }
    if (lane8 == 0) {
      float o0 = acc0 / dsum + b2[0];
      float o1 = acc1 / dsum + b2[1];
      int g = load_idx(batch, n, b64);
      atomicAdd(&psum[g * 2], o0);
      atomicAdd(&psum[g * 2 + 1], o1);
      atomicAdd(&pcnt[g], 1.f);
    }
  }
  __syncthreads();
  if (t < 64 && pcnt[t] > 0.f) {
    atomicAdd(&pool[t * 2], psum[t * 2]);
    atomicAdd(&pool[t * 2 + 1], psum[t * 2 + 1]);
    atomicAdd(&pool[128 + t], pcnt[t]);
  }
}

// ---------- mean + log_softmax ----------
__global__ void finalize_kernel(const float* __restrict__ pool, float* __restrict__ out) {
  int g = threadIdx.x;
  if (g < 64) {
    float c = fmaxf(pool[128 + g], 1.f);
    float p0 = pool[g * 2] / c, p1 = pool[g * 2 + 1] / c;
    float m = fmaxf(p0, p1);
    float lse = m + logf(expf(p0 - m) + expf(p1 - m));
    out[g * 2] = p0 - lse;
    out[g * 2 + 1] = p1 - lse;
  }
}

extern "C" void kernel_launch(void* const* d_in, const int* in_sizes, int n_in,
                              void* d_out, int out_size, void* d_ws, size_t ws_size,
                              hipStream_t stream) {
  const float* x        = (const float*)d_in[0];
  const void* eidx      = d_in[1];
  const void* batch     = d_in[2];
  const float* W1       = (const float*)d_in[3];
  const float* att_src1 = (const float*)d_in[4];
  const float* att_dst1 = (const float*)d_in[5];
  const float* b1       = (const float*)d_in[6];
  const float* W2       = (const float*)d_in[7];
  const float* att_src2 = (const float*)d_in[8];
  const float* att_dst2 = (const float*)d_in[9];
  const float* b2       = (const float*)d_in[10];
  float* out = (float*)d_out;

  int N = in_sizes[0] / 128;
  int E = in_sizes[1] / 2;
  int EP = E + N;
  int NBUK = (N + 255) >> 8;         // <= MAXBUK for N <= 131072
  int NC = NBUK * NBLK;
  int chunk = (((EP + NBLK - 1) / NBLK) + 1) & ~1;   // even, <= CHUNK_MAX

  char* ws = (char*)d_ws;
  size_t o = 0;
  auto alloc = [&](size_t bytes) -> void* {
    void* p = ws + o;
    o += (bytes + 255) & ~(size_t)255;
    return p;
  };
  u16*   h      = (u16*)alloc((size_t)N * 128 * 2);    // 25.6 MB bf16
  u16*   Wtb    = (u16*)alloc(128 * 128 * 2);          // bf16 W1^T
  float* a_src1 = (float*)alloc((size_t)N * 8 * 4);
  float* a_dst1 = (float*)alloc((size_t)N * 8 * 4);
  int*   offs   = (int*)alloc((size_t)N * 4);
  int*   ends   = (int*)alloc((size_t)N * 4);
  int*   hist_g = (int*)alloc((size_t)NC * 4);         // 400 KB
  int*   pbase  = (int*)alloc((size_t)NC * 4);         // partial scan
  int*   bsums  = (int*)alloc((size_t)(NBUK + 1) * 4);
  u32*   pairs  = (u32*)alloc((size_t)EP * 4);         // 6.8 MB packed
  int*   ssrc   = (int*)alloc((size_t)EP * 4);
  float4* rec   = (float4*)alloc((size_t)N * 16);      // {p0,p1,as2,ad2}
  float* pool   = (float*)alloc(192 * 4);
  int*   flags  = (int*)alloc(2 * 4);

  prep_kernel<<<65, 256, 0, stream>>>(eidx, 2 * E, batch, N, W1, Wtb, pool, flags);
  gemm1_kernel<<<(N + 63) / 64, 256, 0, stream>>>(x, Wtb, att_src1, att_dst1,
                                                  h, a_src1, a_dst1, N);
  ehist_kernel<<<NBLK, 512, 0, stream>>>(eidx, E, EP, chunk, flags, hist_g, NBUK);
  scan_blk<<<NBUK, 256, 0, stream>>>(hist_g, pbase, bsums, NC);
  scan_top<<<1, 1024, 0, stream>>>(bsums, NBUK);
  escatter_kernel<<<NBLK, 512, 0, stream>>>(eidx, E, EP, chunk, flags, hist_g,
                                            pbase, bsums, pairs, NBUK);
  bfinal_kernel<<<NBUK, 256, 0, stream>>>(pairs, pbase, bsums, offs, ends, ssrc,
                                          N, EP, NBUK);
  node1_kernel<<<(N + 15) / 16, 256, 0, stream>>>(ssrc, offs, ends, h, a_src1, a_dst1,
                                                  b1, W2, att_src2, att_dst2,
                                                  rec, N);
  node2_kernel<<<(N + 31) / 32, 256, 0, stream>>>(ssrc, offs, ends, rec,
                                                  b2, batch, flags, pool, N);
  finalize_kernel<<<1, 64, 0, stream>>>(pool, out);
}